// Round 5
// baseline (262.708 us; speedup 1.0000x reference)
//
#include <hip/hip_runtime.h>

#define BB 8
#define HH 1024
#define WW 1024
#define HW (HH*WW)
#define PI_F 3.14159265358979323846f

static __device__ __forceinline__ void gload16(const float* g, float* l)
{
    __builtin_amdgcn_global_load_lds(
        (const __attribute__((address_space(1))) void*)g,
        (__attribute__((address_space(3))) void*)l,
        16, 0, 0);
}

// ---------------------------------------------------------------------------
// Twiddle table + NRM zeroing. Per-stage concatenated: stage with half-span
// len at offset (1024-2*len), len entries exp(-i*pi*j/len)
// ---------------------------------------------------------------------------
__global__ __launch_bounds__(256) void k_twid(float2* __restrict__ tw,
                                              float* __restrict__ nrm)
{
    int tid = blockIdx.x * 256 + threadIdx.x;   // 1024 threads
    if (tid < 16) nrm[tid] = 0.0f;
    for (int len = 512; len >= 1; len >>= 1) {
        int off = 1024 - 2 * len;
        float fac = -PI_F / (float)len;
        for (int j = tid; j < len; j += 1024) {
            float sn, cs;
            sincosf(fac * (float)j, &sn, &cs);
            tw[off + j] = make_float2(cs, sn);
        }
    }
}

// ---------------------------------------------------------------------------
// Fused 3x diffusion of f_u/f_v + L2 norm — full-width band register-march.
// (unchanged — measured near its floor)
// ---------------------------------------------------------------------------
#define RBAND 8
#define RAWROWS 14          // RBAND + 6

__global__ __launch_bounds__(256) void k_diff3(const float* __restrict__ su,
                                               const float* __restrict__ sv,
                                               float* __restrict__ dst,
                                               float* __restrict__ norms)
{
    __shared__ __align__(16) float A[RAWROWS * WW];   // 56 KB
    __shared__ float wsum[4];

    int bid = blockIdx.x;
    int work = (bid & 7) * 256 + (bid >> 3);
    int z = work >> 7;            // f*8+b, 0..15
    int band = work & 127;
    int f = z >> 3, b = z & 7;
    const float* s = ((f == 0) ? su : sv) + (size_t)b * HW;
    float* d = dst + (size_t)z * HW;
    int yb = band * RBAND;
    int tid = threadIdx.x;
    int w = tid >> 6, lane = tid & 63;

    for (int c = w; c < RAWROWS * 4; c += 4) {
        int row = c >> 2, seg = c & 3;
        const float* g = s + (size_t)((yb - 3 + row) & (HH - 1)) * WW
                           + (seg << 8) + (lane << 2);
        gload16(g, &A[(c << 8) + (lane << 2)]);
    }
    __syncthreads();

    const char* Ab = (const char*)A;
    int xq = tid << 4;
    int om = (xq - 16) & 4095;
    int op = (xq + 16) & 4095;

    float r[3][12];
    float i1[3][8];
    float i2[3][6];
    float sq = 0.0f;

    #pragma unroll
    for (int j = 0; j < RAWROWS; ++j) {
        {
            float4 a = *(const float4*)(Ab + j * 4096 + om);
            float4 bq = *(const float4*)(Ab + j * 4096 + xq);
            float4 cq = *(const float4*)(Ab + j * 4096 + op);
            float* rr = r[j % 3];
            rr[0] = a.x; rr[1] = a.y; rr[2] = a.z; rr[3] = a.w;
            rr[4] = bq.x; rr[5] = bq.y; rr[6] = bq.z; rr[7] = bq.w;
            rr[8] = cq.x; rr[9] = cq.y; rr[10] = cq.z; rr[11] = cq.w;
        }
        if (j >= 2) {
            const float* ru = r[(j - 2) % 3];
            const float* rc = r[(j - 1) % 3];
            const float* rd = r[j % 3];
            float* o = i1[(j - 1) % 3];
            #pragma unroll
            for (int k = 0; k < 8; ++k) {
                float c0 = rc[k + 2];
                o[k] = c0 + 0.1f * (rc[k + 1] + rc[k + 3] + ru[k + 2] + rd[k + 2] - 4.0f * c0);
            }
        }
        if (j >= 4) {
            const float* u = i1[(j - 3) % 3];
            const float* c = i1[(j - 2) % 3];
            const float* dd = i1[(j - 1) % 3];
            float* o = i2[(j - 2) % 3];
            #pragma unroll
            for (int k = 0; k < 6; ++k) {
                float c0 = c[k + 1];
                o[k] = c0 + 0.1f * (c[k] + c[k + 2] + u[k + 1] + dd[k + 1] - 4.0f * c0);
            }
        }
        if (j >= 6) {
            const float* u = i2[(j - 4) % 3];
            const float* c = i2[(j - 3) % 3];
            const float* dd = i2[(j - 2) % 3];
            float4 o;
            float* op4 = (float*)&o;
            #pragma unroll
            for (int k = 0; k < 4; ++k) {
                float c0 = c[k + 1];
                op4[k] = c0 + 0.1f * (c[k] + c[k + 2] + u[k + 1] + dd[k + 1] - 4.0f * c0);
            }
            *(float4*)(d + (size_t)(yb + j - 6) * WW + (tid << 2)) = o;
            sq += o.x * o.x + o.y * o.y + o.z * o.z + o.w * o.w;
        }
    }

    #pragma unroll
    for (int o = 32; o > 0; o >>= 1) sq += __shfl_down(sq, o, 64);
    if (lane == 0) wsum[w] = sq;
    __syncthreads();
    if (tid == 0)
        atomicAdd(&norms[z], wsum[0] + wsum[1] + wsum[2] + wsum[3]);
}

// ---------------------------------------------------------------------------
// float2-based FFT helpers (length 1024, LDS, 256 threads)
// ---------------------------------------------------------------------------
static __device__ __forceinline__ void fft_dif2(float2* d, const float2* tw)
{
    int t = threadIdx.x;
    for (int s = 9; s >= 0; --s) {
        int len = 1 << s;
        int off = 1024 - 2 * len;
        __syncthreads();
        #pragma unroll
        for (int k = 0; k < 2; ++k) {
            int bt = t + (k << 8);
            int j = bt & (len - 1);
            int i = ((bt >> s) << (s + 1)) | j;
            float2 u = d[i], v = d[i + len], w = tw[off + j];
            d[i] = make_float2(u.x + v.x, u.y + v.y);
            float dr = u.x - v.x, di = u.y - v.y;
            d[i + len] = make_float2(dr * w.x - di * w.y, dr * w.y + di * w.x);
        }
    }
}

static __device__ __forceinline__ void fft_dit_inv2(float2* d, const float2* tw)
{
    int t = threadIdx.x;
    for (int s = 0; s <= 9; ++s) {
        int len = 1 << s;
        int off = 1024 - 2 * len;
        __syncthreads();
        #pragma unroll
        for (int k = 0; k < 2; ++k) {
            int bt = t + (k << 8);
            int j = bt & (len - 1);
            int i = ((bt >> s) << (s + 1)) | j;
            float2 u = d[i], v = d[i + len], w = tw[off + j];   // conj(w)
            float tr = v.x * w.x + v.y * w.y;
            float ti = v.y * w.x - v.x * w.y;
            d[i] = make_float2(u.x + tr, u.y + ti);
            d[i + len] = make_float2(u.x - tr, u.y - ti);
        }
    }
}

// ---------------------------------------------------------------------------
// Star for one row of one batch (quad-vectorized; x-neighbors via shfl +
// 2-lane global boundary reload). Outputs un[4], vn[4].
// ---------------------------------------------------------------------------
static __device__ __forceinline__ void star_row(
    const float* __restrict__ u, const float* __restrict__ v,
    const float* __restrict__ p, const float* __restrict__ Fu,
    const float* __restrict__ Fv, int y, int xq, int lane,
    float sb, float inu, float inv, float* un, float* vn)
{
    int yr = (y & (HH - 1)) * WW;
    int ym = ((y - 1) & (HH - 1)) * WW;
    int yp = ((y + 1) & (HH - 1)) * WW;

    float4 ucq = *(const float4*)(u + yr + xq);
    float4 uuq = *(const float4*)(u + ym + xq);
    float4 udq = *(const float4*)(u + yp + xq);
    float4 vcq = *(const float4*)(v + yr + xq);
    float4 vuq = *(const float4*)(v + ym + xq);
    float4 vdq = *(const float4*)(v + yp + xq);
    float4 pcq = *(const float4*)(p + yr + xq);
    float4 puq = *(const float4*)(p + ym + xq);
    float4 pdq = *(const float4*)(p + yp + xq);
    float4 fuq = *(const float4*)(Fu + yr + xq);
    float4 fvq = *(const float4*)(Fv + yr + xq);

    float ulf = __shfl_up(ucq.w, 1, 64), urt = __shfl_down(ucq.x, 1, 64);
    float vlf = __shfl_up(vcq.w, 1, 64), vrt = __shfl_down(vcq.x, 1, 64);
    float plf = __shfl_up(pcq.w, 1, 64), prt = __shfl_down(pcq.x, 1, 64);
    if (lane == 0)  { int xm = (xq - 1) & (WW - 1); ulf = u[yr + xm]; vlf = v[yr + xm]; plf = p[yr + xm]; }
    if (lane == 63) { int xp = (xq + 4) & (WW - 1); urt = u[yr + xp]; vrt = v[yr + xp]; prt = p[yr + xp]; }

    float ue[6] = { ulf, ucq.x, ucq.y, ucq.z, ucq.w, urt };
    float ve[6] = { vlf, vcq.x, vcq.y, vcq.z, vcq.w, vrt };
    float pe[6] = { plf, pcq.x, pcq.y, pcq.z, pcq.w, prt };
    float uu_[4] = { uuq.x, uuq.y, uuq.z, uuq.w };
    float ud_[4] = { udq.x, udq.y, udq.z, udq.w };
    float vu_[4] = { vuq.x, vuq.y, vuq.z, vuq.w };
    float vd_[4] = { vdq.x, vdq.y, vdq.z, vdq.w };
    float pu_[4] = { puq.x, puq.y, puq.z, puq.w };
    float pd_[4] = { pdq.x, pdq.y, pdq.z, pdq.w };
    float fu_[4] = { fuq.x, fuq.y, fuq.z, fuq.w };
    float fv_[4] = { fvq.x, fvq.y, fvq.z, fvq.w };

    #pragma unroll
    for (int k = 0; k < 4; ++k) {
        float ucc = ue[k + 1], vcc = ve[k + 1];
        float adv_u = ucc * (0.5f * (ue[k + 2] - ue[k])) + vcc * (0.5f * (ud_[k] - uu_[k]));
        float adv_v = ucc * (0.5f * (ve[k + 2] - ve[k])) + vcc * (0.5f * (vd_[k] - vu_[k]));
        float lap_u = ue[k] + ue[k + 2] + uu_[k] + ud_[k] - 4.0f * ucc;
        float lap_v = ve[k] + ve[k + 2] + vu_[k] + vd_[k] - 4.0f * vcc;
        float dpdx = 0.5f * (pe[k + 2] - pe[k]);
        float dpdy = 0.5f * (pd_[k] - pu_[k]);
        un[k] = ucc + 0.01f * (-adv_u + 0.01f * lap_u - dpdx) + sb * fu_[k] * inu;
        vn[k] = vcc + 0.01f * (-adv_v + 0.01f * lap_v - dpdy) + sb * fv_[k] * inv;
    }
}

// ---------------------------------------------------------------------------
// Fused star + divergence + forward row FFT. Block = (band of 4 rows, pair q).
// Star rows j=0..5 (y = y0-1+j): vn kept in rotating registers (no x-nbrs
// needed), un x-nbrs via shfl + per-wave edge LDS. Owned UV rows (j=1..4)
// written for k_ifinal. Div row r=y0+j-2 (j>=2) packed d(b0)+i*d(b1) into
// LDS and row-FFT'd immediately; spec row written bit-reversed.
// All slot overwrites fenced by the FFT's internal stage barriers.
// ---------------------------------------------------------------------------
#define SB 4                 // output rows per block

__global__ __launch_bounds__(256) void k_stardiv(const float* __restrict__ X,
                                                 const float* __restrict__ beta,
                                                 const float* __restrict__ F,
                                                 const float* __restrict__ norms,
                                                 float* __restrict__ UV,
                                                 float2* __restrict__ spec,
                                                 const float2* __restrict__ tw)
{
    __shared__ __align__(16) float2 data[1024];      // 8 KB
    __shared__ __align__(16) float2 twl[1024];       // 8 KB
    __shared__ float edgeL[2][2][4], edgeR[2][2][4]; // [slot][batch][cons.wave]

    // XCD swizzle: 1024 works; each XCD gets 128 consecutive (q, band) works
    int bid = blockIdx.x;
    int work = (bid & 7) * 128 + (bid >> 3);
    int q = work >> 8;            // pair 0..3
    int band = work & 255;
    int y0 = band * SB;
    int b0 = 2 * q, b1 = 2 * q + 1;
    int tid = threadIdx.x, w = tid >> 6, lane = tid & 63;
    int xq = tid << 2;

    for (int j = tid; j < 1024; j += 256) twl[j] = tw[j];

    const float* u0g = X + (size_t)(b0 * 3 + 0) * HW;
    const float* v0g = X + (size_t)(b0 * 3 + 1) * HW;
    const float* p0g = X + (size_t)(b0 * 3 + 2) * HW;
    const float* u1g = X + (size_t)(b1 * 3 + 0) * HW;
    const float* v1g = X + (size_t)(b1 * 3 + 1) * HW;
    const float* p1g = X + (size_t)(b1 * 3 + 2) * HW;
    const float* Fu0 = F + (size_t)(0 * BB + b0) * HW;
    const float* Fv0 = F + (size_t)(1 * BB + b0) * HW;
    const float* Fu1 = F + (size_t)(0 * BB + b1) * HW;
    const float* Fv1 = F + (size_t)(1 * BB + b1) * HW;

    float sb0 = sqrtf(beta[b0]), sb1 = sqrtf(beta[b1]);
    float inu0 = 1.0f / fmaxf(sqrtf(norms[b0]), 1e-12f);
    float inv0 = 1.0f / fmaxf(sqrtf(norms[BB + b0]), 1e-12f);
    float inu1 = 1.0f / fmaxf(sqrtf(norms[b1]), 1e-12f);
    float inv1 = 1.0f / fmaxf(sqrtf(norms[BB + b1]), 1e-12f);

    float vnA0[4] = {0}, vnB0[4] = {0}, vnC0[4] = {0};
    float vnA1[4] = {0}, vnB1[4] = {0}, vnC1[4] = {0};
    float unP0[4] = {0}, unP1[4] = {0}, unC0[4] = {0}, unC1[4] = {0};

    for (int j = 0; j < SB + 2; ++j) {
        // rotate rings (all static indices)
        #pragma unroll
        for (int k = 0; k < 4; ++k) {
            vnA0[k] = vnB0[k]; vnB0[k] = vnC0[k];
            vnA1[k] = vnB1[k]; vnB1[k] = vnC1[k];
            unP0[k] = unC0[k]; unP1[k] = unC1[k];
        }

        int y = y0 - 1 + j;
        star_row(u0g, v0g, p0g, Fu0, Fv0, y, xq, lane, sb0, inu0, inv0, unC0, vnC0);
        star_row(u1g, v1g, p1g, Fu1, Fv1, y, xq, lane, sb1, inu1, inv1, unC1, vnC1);

        if (j >= 1 && j <= SB) {
            size_t ro = (size_t)y * WW + xq;
            *(float4*)(UV + (size_t)(0 * BB + b0) * HW + ro) = *(float4*)unC0;
            *(float4*)(UV + (size_t)(1 * BB + b0) * HW + ro) = *(float4*)vnC0;
            *(float4*)(UV + (size_t)(0 * BB + b1) * HW + ro) = *(float4*)unC1;
            *(float4*)(UV + (size_t)(1 * BB + b1) * HW + ro) = *(float4*)vnC1;
        }

        // publish un edges for next-step div (slot j&1)
        if (lane == 63) {
            edgeL[j & 1][0][(w + 1) & 3] = unC0[3];
            edgeL[j & 1][1][(w + 1) & 3] = unC1[3];
        }
        if (lane == 0) {
            edgeR[j & 1][0][(w + 3) & 3] = unC0[0];
            edgeR[j & 1][1][(w + 3) & 3] = unC1[0];
        }
        __syncthreads();   // edges visible; fences prev iter's data[] readers

        if (j >= 2) {
            int slot = (j - 1) & 1;
            float lf0 = __shfl_up(unP0[3], 1, 64), rt0 = __shfl_down(unP0[0], 1, 64);
            float lf1 = __shfl_up(unP1[3], 1, 64), rt1 = __shfl_down(unP1[0], 1, 64);
            if (lane == 0)  { lf0 = edgeL[slot][0][w]; lf1 = edgeL[slot][1][w]; }
            if (lane == 63) { rt0 = edgeR[slot][0][w]; rt1 = edgeR[slot][1][w]; }
            float e0[6] = { lf0, unP0[0], unP0[1], unP0[2], unP0[3], rt0 };
            float e1[6] = { lf1, unP1[0], unP1[1], unP1[2], unP1[3], rt1 };
            #pragma unroll
            for (int k = 0; k < 4; ++k) {
                float d0 = 0.5f * (e0[k + 2] - e0[k]) + 0.5f * (vnC0[k] - vnA0[k]);
                float d1 = 0.5f * (e1[k + 2] - e1[k]) + 0.5f * (vnC1[k] - vnA1[k]);
                data[xq + k] = make_float2(d0, d1);
            }

            fft_dif2(data, twl);   // first stage barrier makes pack visible
            __syncthreads();       // fft results visible

            int r = y0 + j - 2;
            size_t base = (size_t)((q << 10) + r) << 10;
            float4* dst4 = (float4*)(spec + base);
            float4* dat4 = (float4*)data;
            dst4[2 * tid] = dat4[2 * tid];
            dst4[2 * tid + 1] = dat4[2 * tid + 1];
        }
    }
}

// ---------------------------------------------------------------------------
// Pass B (transposed): col FFT, Poisson scale, inverse col FFT. In place.
// ---------------------------------------------------------------------------
__global__ __launch_bounds__(256) void k_fft_poisson(float2* __restrict__ data_g,
                                                     const float2* __restrict__ tw)
{
    __shared__ __align__(16) float2 data[1024];
    __shared__ __align__(16) float2 twl[1024];
    int r = blockIdx.x;
    int i = r & 1023;
    int kx = __brev((unsigned)i) >> 22;
    int fx = (kx < 512) ? kx : kx - 1024;
    float fx2 = (float)(fx * fx);
    size_t base = (size_t)r * 1024;
    int tid = threadIdx.x, w = tid >> 6, lane = tid & 63;

    const float* g = (const float*)(data_g + base);
    for (int c = w; c < 8; c += 4)
        gload16(g + (c << 8) + (lane << 2), ((float*)data) + (c << 8) + (lane << 2));
    for (int j = tid; j < 1024; j += 256) twl[j] = tw[j];

    fft_dif2(data, twl);    // first barrier drains DMA + twl
    __syncthreads();
    const float c = -1.0f / (4.0f * PI_F * PI_F * 1024.0f * 1024.0f); // incl. 1/(H*W)
    for (int k = tid; k < 1024; k += 256) {
        int ky = __brev((unsigned)k) >> 22;
        int fy = (ky < 512) ? ky : ky - 1024;
        float k2 = fx2 + (float)(fy * fy);
        float s = (k2 > 0.0f) ? (c / k2) : 0.0f;   // DC zeroed
        float2 v = data[k];
        data[k] = make_float2(v.x * s, v.y * s);
    }
    fft_dit_inv2(data, twl);
    __syncthreads();
    float4* dg4 = (float4*)(data_g + base);
    float4* dat4 = (float4*)data;
    dg4[2 * tid] = dat4[2 * tid];
    dg4[2 * tid + 1] = dat4[2 * tid + 1];
}

// ---------------------------------------------------------------------------
// Per-image complex transpose, 32x32 tiles (4 packed images)
// ---------------------------------------------------------------------------
__global__ __launch_bounds__(256) void k_transpose(const float2* __restrict__ src,
                                                   float2* __restrict__ dst)
{
    __shared__ float2 tile[32][33];
    size_t ib = (size_t)blockIdx.z * (size_t)HW;
    int x = blockIdx.x * 32 + threadIdx.x;
    int y0 = blockIdx.y * 32 + threadIdx.y;
    #pragma unroll
    for (int k = 0; k < 4; ++k)
        tile[threadIdx.y + 8 * k][threadIdx.x] = src[ib + (size_t)(y0 + 8 * k) * WW + x];
    __syncthreads();
    int x2 = blockIdx.y * 32 + threadIdx.x;
    int y2 = blockIdx.x * 32 + threadIdx.y;
    #pragma unroll
    for (int k = 0; k < 4; ++k)
        dst[ib + (size_t)(y2 + 8 * k) * WW + x2] = tile[threadIdx.x][threadIdx.y + 8 * k];
}

// ---------------------------------------------------------------------------
// Fused inverse row FFT + final projection. Block = (band of FBAND rows, q).
// (unchanged from round 4)
// ---------------------------------------------------------------------------
#define FBAND 4

__global__ __launch_bounds__(256) void k_ifinal(const float2* __restrict__ spec,
                                                const float* __restrict__ UV,
                                                const float* __restrict__ X,
                                                float* __restrict__ out,
                                                const float2* __restrict__ tw)
{
    __shared__ __align__(16) float2 ring[3][1024];   // 24 KB
    __shared__ __align__(16) float2 twl[1024];       // 8 KB
    int band = blockIdx.x, q = blockIdx.y;
    int b0 = 2 * q, b1 = 2 * q + 1;
    int y0 = band * FBAND;
    int tid = threadIdx.x, w = tid >> 6, lane = tid & 63;

    for (int j = tid; j < 1024; j += 256) twl[j] = tw[j];

    size_t sbase = (size_t)q * HW;
    const float* u0 = UV + (size_t)(0 * BB + b0) * HW;
    const float* v0 = UV + (size_t)(BB + b0) * HW;
    const float* u1 = UV + (size_t)(0 * BB + b1) * HW;
    const float* v1 = UV + (size_t)(BB + b1) * HW;
    const float* p0 = X + (size_t)(b0 * 3 + 2) * HW;
    const float* p1 = X + (size_t)(b1 * 3 + 2) * HW;
    float* o_u0 = out + (size_t)(b0 * 3 + 0) * HW;
    float* o_v0 = out + (size_t)(b0 * 3 + 1) * HW;
    float* o_p0 = out + (size_t)(b0 * 3 + 2) * HW;
    float* o_u1 = out + (size_t)(b1 * 3 + 0) * HW;
    float* o_v1 = out + (size_t)(b1 * 3 + 1) * HW;
    float* o_p1 = out + (size_t)(b1 * 3 + 2) * HW;

    for (int rr = 0; rr < FBAND + 2; ++rr) {
        int yg = (y0 - 1 + rr) & (HH - 1);
        float2* slot = ring[rr % 3];

        __syncthreads();   // prior emit readers done before overwriting oldest slot
        const float* g = (const float*)(spec + sbase + (size_t)yg * 1024);
        for (int cch = w; cch < 8; cch += 4)
            gload16(g + (cch << 8) + (lane << 2), ((float*)slot) + (cch << 8) + (lane << 2));

        fft_dit_inv2(slot, twl);   // internal stage barriers drain DMA first
        __syncthreads();           // slot complete

        if (rr >= 2) {
            int ye = y0 + rr - 2;
            const float2* pcn = ring[(rr - 1) % 3];   // row ye
            const float2* ppm = ring[(rr - 2) % 3];   // row ye-1
            const float2* ppp = ring[rr % 3];         // row ye+1
            int xq = tid << 2;

            float4 cA = *(const float4*)&pcn[xq];
            float4 cB = *(const float4*)&pcn[xq + 2];
            float4 uA = *(const float4*)&ppm[xq];
            float4 uB = *(const float4*)&ppm[xq + 2];
            float4 dA = *(const float4*)&ppp[xq];
            float4 dB = *(const float4*)&ppp[xq + 2];
            float2 lf = pcn[(xq - 1) & 1023];
            float2 rt = pcn[(xq + 4) & 1023];

            float c0[4] = { cA.x, cA.z, cB.x, cB.z }, c1[4] = { cA.y, cA.w, cB.y, cB.w };
            float um0[4] = { uA.x, uA.z, uB.x, uB.z }, um1[4] = { uA.y, uA.w, uB.y, uB.w };
            float dp0[4] = { dA.x, dA.z, dB.x, dB.z }, dp1[4] = { dA.y, dA.w, dB.y, dB.w };
            float e0[6] = { lf.x, c0[0], c0[1], c0[2], c0[3], rt.x };
            float e1[6] = { lf.y, c1[0], c1[1], c1[2], c1[3], rt.y };

            size_t ro = (size_t)ye * WW + xq;
            float4 u0q = *(const float4*)(u0 + ro);
            float4 v0q = *(const float4*)(v0 + ro);
            float4 u1q = *(const float4*)(u1 + ro);
            float4 v1q = *(const float4*)(v1 + ro);
            float4 p0q = *(const float4*)(p0 + ro);
            float4 p1q = *(const float4*)(p1 + ro);

            float4 ou0, ov0, op0, ou1, ov1, op1;
            #pragma unroll
            for (int k = 0; k < 4; ++k) {
                ((float*)&ou0)[k] = ((float*)&u0q)[k] - 0.5f * (e0[k + 2] - e0[k]);
                ((float*)&ov0)[k] = ((float*)&v0q)[k] - 0.5f * (dp0[k] - um0[k]);
                ((float*)&op0)[k] = ((float*)&p0q)[k] + c0[k];
                ((float*)&ou1)[k] = ((float*)&u1q)[k] - 0.5f * (e1[k + 2] - e1[k]);
                ((float*)&ov1)[k] = ((float*)&v1q)[k] - 0.5f * (dp1[k] - um1[k]);
                ((float*)&op1)[k] = ((float*)&p1q)[k] + c1[k];
            }
            *(float4*)(o_u0 + ro) = ou0;
            *(float4*)(o_v0 + ro) = ov0;
            *(float4*)(o_p0 + ro) = op0;
            *(float4*)(o_u1 + ro) = ou1;
            *(float4*)(o_v1 + ro) = ov1;
            *(float4*)(o_p1 + ro) = op1;
        }
    }
}

extern "C" void kernel_launch(void* const* d_in, const int* in_sizes, int n_in,
                              void* d_out, int out_size, void* d_ws, size_t ws_size,
                              hipStream_t stream)
{
    const float* X    = (const float*)d_in[0];
    const float* beta = (const float*)d_in[1];
    const float* fu   = (const float*)d_in[2];
    const float* fv   = (const float*)d_in[3];
    float* out = (float*)d_out;
    float* ws  = (float*)d_ws;

    float* F1  = ws;                              // 16M floats (64MB)
    float* UV  = F1 + (size_t)2 * BB * HW;        // 16M floats (64MB)
    float* Dpf = UV + (size_t)2 * BB * HW;        // 8M floats  (32MB, 4 complex imgs)
    float* Cbf = Dpf + (size_t)BB * HW;           // 8M floats  (32MB)
    float* TWf = Cbf + (size_t)BB * HW;           // 2048 floats
    float* NRM = TWf + 2048;                      // 16 floats
    float2* Dp = (float2*)Dpf;
    float2* Cb = (float2*)Cbf;
    float2* TW = (float2*)TWf;

    k_twid<<<4, 256, 0, stream>>>(TW, NRM);

    dim3 blk(256);
    dim3 tgrid(32, 32, BB / 2), tblk(32, 8);

    k_diff3<<<2048, blk, 0, stream>>>(fu, fv, F1, NRM);
    k_stardiv<<<1024, blk, 0, stream>>>(X, beta, F1, NRM, UV, Cb, TW);

    k_transpose<<<tgrid, tblk, 0, stream>>>(Cb, Dp);
    k_fft_poisson<<<(BB / 2) * HH, blk, 0, stream>>>(Dp, TW);
    k_transpose<<<tgrid, tblk, 0, stream>>>(Dp, Cb);
    k_ifinal<<<dim3(HH / FBAND, BB / 2), blk, 0, stream>>>(Cb, UV, X, out, TW);
}

// Round 7
// 222.856 us; speedup vs baseline: 1.1788x; 1.1788x over previous
//
#include <hip/hip_runtime.h>

#define BB 8
#define HH 1024
#define WW 1024
#define HW (HH*WW)
#define PI_F 3.14159265358979323846f

static __device__ __forceinline__ void gload16(const float* g, float* l)
{
    __builtin_amdgcn_global_load_lds(
        (const __attribute__((address_space(1))) void*)g,
        (__attribute__((address_space(3))) void*)l,
        16, 0, 0);
}

// ---------------------------------------------------------------------------
// Twiddle table + NRM zeroing. Per-stage concatenated: stage with half-span
// len at offset (1024-2*len), len entries exp(-i*pi*j/len)
// ---------------------------------------------------------------------------
__global__ __launch_bounds__(256) void k_twid(float2* __restrict__ tw,
                                              float* __restrict__ nrm)
{
    int tid = blockIdx.x * 256 + threadIdx.x;   // 1024 threads
    if (tid < 16) nrm[tid] = 0.0f;
    for (int len = 512; len >= 1; len >>= 1) {
        int off = 1024 - 2 * len;
        float fac = -PI_F / (float)len;
        for (int j = tid; j < len; j += 1024) {
            float sn, cs;
            sincosf(fac * (float)j, &sn, &cs);
            tw[off + j] = make_float2(cs, sn);
        }
    }
}

// ---------------------------------------------------------------------------
// Fused 3x diffusion of f_u/f_v + L2 norm — full-width band register-march.
// (unchanged — measured near its floor)
// ---------------------------------------------------------------------------
#define RBAND 8
#define RAWROWS 14          // RBAND + 6

__global__ __launch_bounds__(256) void k_diff3(const float* __restrict__ su,
                                               const float* __restrict__ sv,
                                               float* __restrict__ dst,
                                               float* __restrict__ norms)
{
    __shared__ __align__(16) float A[RAWROWS * WW];   // 56 KB
    __shared__ float wsum[4];

    int bid = blockIdx.x;
    int work = (bid & 7) * 256 + (bid >> 3);
    int z = work >> 7;            // f*8+b, 0..15
    int band = work & 127;
    int f = z >> 3, b = z & 7;
    const float* s = ((f == 0) ? su : sv) + (size_t)b * HW;
    float* d = dst + (size_t)z * HW;
    int yb = band * RBAND;
    int tid = threadIdx.x;
    int w = tid >> 6, lane = tid & 63;

    for (int c = w; c < RAWROWS * 4; c += 4) {
        int row = c >> 2, seg = c & 3;
        const float* g = s + (size_t)((yb - 3 + row) & (HH - 1)) * WW
                           + (seg << 8) + (lane << 2);
        gload16(g, &A[(c << 8) + (lane << 2)]);
    }
    __syncthreads();

    const char* Ab = (const char*)A;
    int xq = tid << 4;
    int om = (xq - 16) & 4095;
    int op = (xq + 16) & 4095;

    float r[3][12];
    float i1[3][8];
    float i2[3][6];
    float sq = 0.0f;

    #pragma unroll
    for (int j = 0; j < RAWROWS; ++j) {
        {
            float4 a = *(const float4*)(Ab + j * 4096 + om);
            float4 bq = *(const float4*)(Ab + j * 4096 + xq);
            float4 cq = *(const float4*)(Ab + j * 4096 + op);
            float* rr = r[j % 3];
            rr[0] = a.x; rr[1] = a.y; rr[2] = a.z; rr[3] = a.w;
            rr[4] = bq.x; rr[5] = bq.y; rr[6] = bq.z; rr[7] = bq.w;
            rr[8] = cq.x; rr[9] = cq.y; rr[10] = cq.z; rr[11] = cq.w;
        }
        if (j >= 2) {
            const float* ru = r[(j - 2) % 3];
            const float* rc = r[(j - 1) % 3];
            const float* rd = r[j % 3];
            float* o = i1[(j - 1) % 3];
            #pragma unroll
            for (int k = 0; k < 8; ++k) {
                float c0 = rc[k + 2];
                o[k] = c0 + 0.1f * (rc[k + 1] + rc[k + 3] + ru[k + 2] + rd[k + 2] - 4.0f * c0);
            }
        }
        if (j >= 4) {
            const float* u = i1[(j - 3) % 3];
            const float* c = i1[(j - 2) % 3];
            const float* dd = i1[(j - 1) % 3];
            float* o = i2[(j - 2) % 3];
            #pragma unroll
            for (int k = 0; k < 6; ++k) {
                float c0 = c[k + 1];
                o[k] = c0 + 0.1f * (c[k] + c[k + 2] + u[k + 1] + dd[k + 1] - 4.0f * c0);
            }
        }
        if (j >= 6) {
            const float* u = i2[(j - 4) % 3];
            const float* c = i2[(j - 3) % 3];
            const float* dd = i2[(j - 2) % 3];
            float4 o;
            float* op4 = (float*)&o;
            #pragma unroll
            for (int k = 0; k < 4; ++k) {
                float c0 = c[k + 1];
                op4[k] = c0 + 0.1f * (c[k] + c[k + 2] + u[k + 1] + dd[k + 1] - 4.0f * c0);
            }
            *(float4*)(d + (size_t)(yb + j - 6) * WW + (tid << 2)) = o;
            sq += o.x * o.x + o.y * o.y + o.z * o.z + o.w * o.w;
        }
    }

    #pragma unroll
    for (int o = 32; o > 0; o >>= 1) sq += __shfl_down(sq, o, 64);
    if (lane == 0) wsum[w] = sq;
    __syncthreads();
    if (tid == 0)
        atomicAdd(&norms[z], wsum[0] + wsum[1] + wsum[2] + wsum[3]);
}

// ---------------------------------------------------------------------------
// Star velocities — quad-vectorized, block = one full row. (round-4 version)
// ---------------------------------------------------------------------------
__global__ __launch_bounds__(256) void k_star(const float* __restrict__ X,
                                              const float* __restrict__ beta,
                                              const float* __restrict__ F,
                                              const float* __restrict__ norms,
                                              float* __restrict__ UV)
{
    int b = blockIdx.y;
    int y = blockIdx.x;
    int tid = threadIdx.x;
    int lane = tid & 63;
    int xq = tid << 2;
    const float* u = X + (size_t)(b * 3 + 0) * HW;
    const float* v = X + (size_t)(b * 3 + 1) * HW;
    const float* p = X + (size_t)(b * 3 + 2) * HW;
    int yr = y * WW, ym = ((y - 1) & (HH - 1)) * WW, yp = ((y + 1) & (HH - 1)) * WW;

    float4 ucq = *(const float4*)(u + yr + xq);
    float4 uuq = *(const float4*)(u + ym + xq);
    float4 udq = *(const float4*)(u + yp + xq);
    float4 vcq = *(const float4*)(v + yr + xq);
    float4 vuq = *(const float4*)(v + ym + xq);
    float4 vdq = *(const float4*)(v + yp + xq);
    float4 pcq = *(const float4*)(p + yr + xq);
    float4 puq = *(const float4*)(p + ym + xq);
    float4 pdq = *(const float4*)(p + yp + xq);
    float4 fuq = *(const float4*)(F + (size_t)(0 * BB + b) * HW + yr + xq);
    float4 fvq = *(const float4*)(F + (size_t)(1 * BB + b) * HW + yr + xq);

    float ulf = __shfl_up(ucq.w, 1, 64), urt = __shfl_down(ucq.x, 1, 64);
    float vlf = __shfl_up(vcq.w, 1, 64), vrt = __shfl_down(vcq.x, 1, 64);
    float plf = __shfl_up(pcq.w, 1, 64), prt = __shfl_down(pcq.x, 1, 64);
    if (lane == 0)  { int xm = (xq - 1) & (WW - 1); ulf = u[yr + xm]; vlf = v[yr + xm]; plf = p[yr + xm]; }
    if (lane == 63) { int xp = (xq + 4) & (WW - 1); urt = u[yr + xp]; vrt = v[yr + xp]; prt = p[yr + xp]; }

    float ue[6] = { ulf, ucq.x, ucq.y, ucq.z, ucq.w, urt };
    float ve[6] = { vlf, vcq.x, vcq.y, vcq.z, vcq.w, vrt };
    float pe[6] = { plf, pcq.x, pcq.y, pcq.z, pcq.w, prt };
    float uu_[4] = { uuq.x, uuq.y, uuq.z, uuq.w };
    float ud_[4] = { udq.x, udq.y, udq.z, udq.w };
    float vu_[4] = { vuq.x, vuq.y, vuq.z, vuq.w };
    float vd_[4] = { vdq.x, vdq.y, vdq.z, vdq.w };
    float pu_[4] = { puq.x, puq.y, puq.z, puq.w };
    float pd_[4] = { pdq.x, pdq.y, pdq.z, pdq.w };
    float fu_[4] = { fuq.x, fuq.y, fuq.z, fuq.w };
    float fv_[4] = { fvq.x, fvq.y, fvq.z, fvq.w };

    float sb = sqrtf(beta[b]);
    float inu = 1.0f / fmaxf(sqrtf(norms[b]), 1e-12f);
    float inv = 1.0f / fmaxf(sqrtf(norms[BB + b]), 1e-12f);

    float4 un4, vn4;
    float* unp = (float*)&un4;
    float* vnp = (float*)&vn4;
    #pragma unroll
    for (int k = 0; k < 4; ++k) {
        float ucc = ue[k + 1], vcc = ve[k + 1];
        float adv_u = ucc * (0.5f * (ue[k + 2] - ue[k])) + vcc * (0.5f * (ud_[k] - uu_[k]));
        float adv_v = ucc * (0.5f * (ve[k + 2] - ve[k])) + vcc * (0.5f * (vd_[k] - vu_[k]));
        float lap_u = ue[k] + ue[k + 2] + uu_[k] + ud_[k] - 4.0f * ucc;
        float lap_v = ve[k] + ve[k + 2] + vu_[k] + vd_[k] - 4.0f * vcc;
        float dpdx = 0.5f * (pe[k + 2] - pe[k]);
        float dpdy = 0.5f * (pd_[k] - pu_[k]);
        unp[k] = ucc + 0.01f * (-adv_u + 0.01f * lap_u - dpdx) + sb * fu_[k] * inu;
        vnp[k] = vcc + 0.01f * (-adv_v + 0.01f * lap_v - dpdy) + sb * fv_[k] * inv;
    }

    *(float4*)(UV + (size_t)(0 * BB + b) * HW + yr + xq) = un4;
    *(float4*)(UV + (size_t)(1 * BB + b) * HW + yr + xq) = vn4;
}

// ---------------------------------------------------------------------------
// float2-based FFT helpers (length 1024, LDS, 256 threads, block-wide)
// ---------------------------------------------------------------------------
static __device__ __forceinline__ void fft_dif2(float2* d, const float2* tw)
{
    int t = threadIdx.x;
    for (int s = 9; s >= 0; --s) {
        int len = 1 << s;
        int off = 1024 - 2 * len;
        __syncthreads();
        #pragma unroll
        for (int k = 0; k < 2; ++k) {
            int bt = t + (k << 8);
            int j = bt & (len - 1);
            int i = ((bt >> s) << (s + 1)) | j;
            float2 u = d[i], v = d[i + len], w = tw[off + j];
            d[i] = make_float2(u.x + v.x, u.y + v.y);
            float dr = u.x - v.x, di = u.y - v.y;
            d[i + len] = make_float2(dr * w.x - di * w.y, dr * w.y + di * w.x);
        }
    }
}

static __device__ __forceinline__ void fft_dit_inv2(float2* d, const float2* tw)
{
    int t = threadIdx.x;
    for (int s = 0; s <= 9; ++s) {
        int len = 1 << s;
        int off = 1024 - 2 * len;
        __syncthreads();
        #pragma unroll
        for (int k = 0; k < 2; ++k) {
            int bt = t + (k << 8);
            int j = bt & (len - 1);
            int i = ((bt >> s) << (s + 1)) | j;
            float2 u = d[i], v = d[i + len], w = tw[off + j];   // conj(w)
            float tr = v.x * w.x + v.y * w.y;
            float ti = v.y * w.x - v.x * w.y;
            d[i] = make_float2(u.x + tr, u.y + ti);
            d[i + len] = make_float2(u.x - tr, u.y - ti);
        }
    }
}

// ---------------------------------------------------------------------------
// Fused divergence + forward row FFT. Block = (row y, pair q). (round-4)
// ---------------------------------------------------------------------------
__global__ __launch_bounds__(256) void k_divfft(const float* __restrict__ UV,
                                                float2* __restrict__ dst,
                                                const float2* __restrict__ tw)
{
    __shared__ __align__(16) float2 data[1024];
    __shared__ __align__(16) float2 twl[1024];
    __shared__ __align__(16) float us0[1024], us1[1024];
    int y = blockIdx.x, q = blockIdx.y;
    int b0 = 2 * q, b1 = 2 * q + 1;
    int tid = threadIdx.x, w = tid >> 6, lane = tid & 63;
    int yr = y * WW, ym = ((y - 1) & (HH - 1)) * WW, yp = ((y + 1) & (HH - 1)) * WW;
    const float* u0 = UV + (size_t)b0 * HW;
    const float* v0 = UV + (size_t)(BB + b0) * HW;
    const float* u1 = UV + (size_t)b1 * HW;
    const float* v1 = UV + (size_t)(BB + b1) * HW;

    gload16(u0 + yr + (w << 8) + (lane << 2), &us0[(w << 8) + (lane << 2)]);
    gload16(u1 + yr + (w << 8) + (lane << 2), &us1[(w << 8) + (lane << 2)]);

    for (int j = tid; j < 1024; j += 256) twl[j] = tw[j];

    int xq = tid << 2;
    float4 v0u = *(const float4*)(v0 + ym + xq);
    float4 v0d = *(const float4*)(v0 + yp + xq);
    float4 v1u = *(const float4*)(v1 + ym + xq);
    float4 v1d = *(const float4*)(v1 + yp + xq);
    __syncthreads();   // drains DMA (vmcnt) + twl

    float4 c0 = *(const float4*)&us0[xq];
    float4 c1 = *(const float4*)&us1[xq];
    float lf0 = us0[(xq - 1) & 1023], rt0 = us0[(xq + 4) & 1023];
    float lf1 = us1[(xq - 1) & 1023], rt1 = us1[(xq + 4) & 1023];
    float u0e[6] = { lf0, c0.x, c0.y, c0.z, c0.w, rt0 };
    float u1e[6] = { lf1, c1.x, c1.y, c1.z, c1.w, rt1 };
    float v0u_[4] = { v0u.x, v0u.y, v0u.z, v0u.w };
    float v0d_[4] = { v0d.x, v0d.y, v0d.z, v0d.w };
    float v1u_[4] = { v1u.x, v1u.y, v1u.z, v1u.w };
    float v1d_[4] = { v1d.x, v1d.y, v1d.z, v1d.w };
    #pragma unroll
    for (int k = 0; k < 4; ++k) {
        float d0 = 0.5f * (u0e[k + 2] - u0e[k]) + 0.5f * (v0d_[k] - v0u_[k]);
        float d1 = 0.5f * (u1e[k + 2] - u1e[k]) + 0.5f * (v1d_[k] - v1u_[k]);
        data[xq + k] = make_float2(d0, d1);
    }

    fft_dif2(data, twl);
    __syncthreads();
    size_t base = (size_t)((q << 10) + y) << 10;
    float4* dst4 = (float4*)(dst + base);
    float4* dat4 = (float4*)data;
    dst4[2 * tid] = dat4[2 * tid];
    dst4[2 * tid + 1] = dat4[2 * tid + 1];
}

// ---------------------------------------------------------------------------
// Fused column pass: replaces transpose + col-FFT/Poisson/col-IFFT +
// transpose. Block = 16 columns of one pair-image; 1024 threads (16 waves).
// Load 1024x16 slab (coalesced 128B row segments) into column-major LDS
// (stride 1026 float2 breaks the pow2 bank collision). Each WAVE runs one
// 1024-pt FFT wave-locally: no block barriers, only s_waitcnt lgkmcnt(0)
// (+ sched_barrier, rule-#18 insurance) between stages; waves touch
// disjoint LDS regions. Scale by Poisson factor, inverse FFT, write back.
// ---------------------------------------------------------------------------
#define CT 16
#define CSTR 1026

__global__ __launch_bounds__(1024) void k_colpass(float2* __restrict__ spec,
                                                  const float2* __restrict__ tw)
{
    __shared__ __align__(16) float2 colbuf[CT * CSTR];   // 131328 B
    __shared__ __align__(16) float2 twl[1024];           // 8192 B
    int tile = blockIdx.x, q = blockIdx.y;
    int i0 = tile * CT;
    int tid = threadIdx.x, lane = tid & 63, w = tid >> 6;
    size_t qb = (size_t)q * HW;

    twl[tid] = tw[tid];

    float2* g = spec + qb;
    #pragma unroll 4
    for (int pass = 0; pass < 16; ++pass) {
        int n = (pass << 10) + tid;
        int r = n >> 4, c = n & 15;
        colbuf[c * CSTR + r] = g[(size_t)r * 1024 + i0 + c];
    }
    __syncthreads();

    // --- per-wave column FFT (column i0+w) ---------------------------------
    float2* d = colbuf + w * CSTR;
    int i = i0 + w;
    int kx = __brev((unsigned)i) >> 22;
    int fx = (kx < 512) ? kx : kx - 1024;
    float fx2 = (float)(fx * fx);

    for (int s = 9; s >= 0; --s) {
        int len = 1 << s, off = 1024 - 2 * len;
        asm volatile("s_waitcnt lgkmcnt(0)" ::: "memory");
        __builtin_amdgcn_sched_barrier(0);
        #pragma unroll
        for (int k = 0; k < 8; ++k) {
            int bt = lane + (k << 6);
            int j = bt & (len - 1);
            int ii = ((bt >> s) << (s + 1)) | j;
            float2 u = d[ii], v = d[ii + len], wv = twl[off + j];
            d[ii] = make_float2(u.x + v.x, u.y + v.y);
            float dr = u.x - v.x, di = u.y - v.y;
            d[ii + len] = make_float2(dr * wv.x - di * wv.y, dr * wv.y + di * wv.x);
        }
    }
    asm volatile("s_waitcnt lgkmcnt(0)" ::: "memory");
    __builtin_amdgcn_sched_barrier(0);
    const float cc = -1.0f / (4.0f * PI_F * PI_F * 1024.0f * 1024.0f); // incl. 1/(H*W)
    #pragma unroll
    for (int k = 0; k < 16; ++k) {
        int kk = lane + (k << 6);
        int ky = __brev((unsigned)kk) >> 22;
        int fy = (ky < 512) ? ky : ky - 1024;
        float k2 = fx2 + (float)(fy * fy);
        float s = (k2 > 0.0f) ? (cc / k2) : 0.0f;   // DC zeroed
        float2 v = d[kk];
        d[kk] = make_float2(v.x * s, v.y * s);
    }
    for (int s = 0; s <= 9; ++s) {
        int len = 1 << s, off = 1024 - 2 * len;
        asm volatile("s_waitcnt lgkmcnt(0)" ::: "memory");
        __builtin_amdgcn_sched_barrier(0);
        #pragma unroll
        for (int k = 0; k < 8; ++k) {
            int bt = lane + (k << 6);
            int j = bt & (len - 1);
            int ii = ((bt >> s) << (s + 1)) | j;
            float2 u = d[ii], v = d[ii + len], wv = twl[off + j];   // conj(w)
            float tr = v.x * wv.x + v.y * wv.y;
            float ti = v.y * wv.x - v.x * wv.y;
            d[ii] = make_float2(u.x + tr, u.y + ti);
            d[ii + len] = make_float2(u.x - tr, u.y - ti);
        }
    }
    asm volatile("s_waitcnt lgkmcnt(0)" ::: "memory");
    __builtin_amdgcn_sched_barrier(0);
    __syncthreads();

    #pragma unroll 4
    for (int pass = 0; pass < 16; ++pass) {
        int n = (pass << 10) + tid;
        int r = n >> 4, c = n & 15;
        g[(size_t)r * 1024 + i0 + c] = colbuf[c * CSTR + r];
    }
}

// ---------------------------------------------------------------------------
// Fused inverse row FFT + final projection. Block = (band of FBAND rows, q).
// (unchanged from round 4)
// ---------------------------------------------------------------------------
#define FBAND 4

__global__ __launch_bounds__(256) void k_ifinal(const float2* __restrict__ spec,
                                                const float* __restrict__ UV,
                                                const float* __restrict__ X,
                                                float* __restrict__ out,
                                                const float2* __restrict__ tw)
{
    __shared__ __align__(16) float2 ring[3][1024];   // 24 KB
    __shared__ __align__(16) float2 twl[1024];       // 8 KB
    int band = blockIdx.x, q = blockIdx.y;
    int b0 = 2 * q, b1 = 2 * q + 1;
    int y0 = band * FBAND;
    int tid = threadIdx.x, w = tid >> 6, lane = tid & 63;

    for (int j = tid; j < 1024; j += 256) twl[j] = tw[j];

    size_t sbase = (size_t)q * HW;
    const float* u0 = UV + (size_t)(0 * BB + b0) * HW;
    const float* v0 = UV + (size_t)(BB + b0) * HW;
    const float* u1 = UV + (size_t)(0 * BB + b1) * HW;
    const float* v1 = UV + (size_t)(BB + b1) * HW;
    const float* p0 = X + (size_t)(b0 * 3 + 2) * HW;
    const float* p1 = X + (size_t)(b1 * 3 + 2) * HW;
    float* o_u0 = out + (size_t)(b0 * 3 + 0) * HW;
    float* o_v0 = out + (size_t)(b0 * 3 + 1) * HW;
    float* o_p0 = out + (size_t)(b0 * 3 + 2) * HW;
    float* o_u1 = out + (size_t)(b1 * 3 + 0) * HW;
    float* o_v1 = out + (size_t)(b1 * 3 + 1) * HW;
    float* o_p1 = out + (size_t)(b1 * 3 + 2) * HW;

    for (int rr = 0; rr < FBAND + 2; ++rr) {
        int yg = (y0 - 1 + rr) & (HH - 1);
        float2* slot = ring[rr % 3];

        __syncthreads();   // prior emit readers done before overwriting oldest slot
        const float* g = (const float*)(spec + sbase + (size_t)yg * 1024);
        for (int cch = w; cch < 8; cch += 4)
            gload16(g + (cch << 8) + (lane << 2), ((float*)slot) + (cch << 8) + (lane << 2));

        fft_dit_inv2(slot, twl);   // internal stage barriers drain DMA first
        __syncthreads();           // slot complete

        if (rr >= 2) {
            int ye = y0 + rr - 2;
            const float2* pcn = ring[(rr - 1) % 3];   // row ye
            const float2* ppm = ring[(rr - 2) % 3];   // row ye-1
            const float2* ppp = ring[rr % 3];         // row ye+1
            int xq = tid << 2;

            float4 cA = *(const float4*)&pcn[xq];
            float4 cB = *(const float4*)&pcn[xq + 2];
            float4 uA = *(const float4*)&ppm[xq];
            float4 uB = *(const float4*)&ppm[xq + 2];
            float4 dA = *(const float4*)&ppp[xq];
            float4 dB = *(const float4*)&ppp[xq + 2];
            float2 lf = pcn[(xq - 1) & 1023];
            float2 rt = pcn[(xq + 4) & 1023];

            float c0[4] = { cA.x, cA.z, cB.x, cB.z }, c1[4] = { cA.y, cA.w, cB.y, cB.w };
            float um0[4] = { uA.x, uA.z, uB.x, uB.z }, um1[4] = { uA.y, uA.w, uB.y, uB.w };
            float dp0[4] = { dA.x, dA.z, dB.x, dB.z }, dp1[4] = { dA.y, dA.w, dB.y, dB.w };
            float e0[6] = { lf.x, c0[0], c0[1], c0[2], c0[3], rt.x };
            float e1[6] = { lf.y, c1[0], c1[1], c1[2], c1[3], rt.y };

            size_t ro = (size_t)ye * WW + xq;
            float4 u0q = *(const float4*)(u0 + ro);
            float4 v0q = *(const float4*)(v0 + ro);
            float4 u1q = *(const float4*)(u1 + ro);
            float4 v1q = *(const float4*)(v1 + ro);
            float4 p0q = *(const float4*)(p0 + ro);
            float4 p1q = *(const float4*)(p1 + ro);

            float4 ou0, ov0, op0, ou1, ov1, op1;
            #pragma unroll
            for (int k = 0; k < 4; ++k) {
                ((float*)&ou0)[k] = ((float*)&u0q)[k] - 0.5f * (e0[k + 2] - e0[k]);
                ((float*)&ov0)[k] = ((float*)&v0q)[k] - 0.5f * (dp0[k] - um0[k]);
                ((float*)&op0)[k] = ((float*)&p0q)[k] + c0[k];
                ((float*)&ou1)[k] = ((float*)&u1q)[k] - 0.5f * (e1[k + 2] - e1[k]);
                ((float*)&ov1)[k] = ((float*)&v1q)[k] - 0.5f * (dp1[k] - um1[k]);
                ((float*)&op1)[k] = ((float*)&p1q)[k] + c1[k];
            }
            *(float4*)(o_u0 + ro) = ou0;
            *(float4*)(o_v0 + ro) = ov0;
            *(float4*)(o_p0 + ro) = op0;
            *(float4*)(o_u1 + ro) = ou1;
            *(float4*)(o_v1 + ro) = ov1;
            *(float4*)(o_p1 + ro) = op1;
        }
    }
}

extern "C" void kernel_launch(void* const* d_in, const int* in_sizes, int n_in,
                              void* d_out, int out_size, void* d_ws, size_t ws_size,
                              hipStream_t stream)
{
    const float* X    = (const float*)d_in[0];
    const float* beta = (const float*)d_in[1];
    const float* fu   = (const float*)d_in[2];
    const float* fv   = (const float*)d_in[3];
    float* out = (float*)d_out;
    float* ws  = (float*)d_ws;

    float* F1  = ws;                              // 16M floats (64MB)
    float* UV  = F1 + (size_t)2 * BB * HW;        // 16M floats (64MB)
    float* Dpf = UV + (size_t)2 * BB * HW;        // 8M floats  (unused now)
    float* Cbf = Dpf + (size_t)BB * HW;           // 8M floats  (32MB)
    float* TWf = Cbf + (size_t)BB * HW;           // 2048 floats
    float* NRM = TWf + 2048;                      // 16 floats
    float2* Cb = (float2*)Cbf;
    float2* TW = (float2*)TWf;

    k_twid<<<4, 256, 0, stream>>>(TW, NRM);

    dim3 blk(256);

    k_diff3<<<2048, blk, 0, stream>>>(fu, fv, F1, NRM);
    k_star<<<dim3(HH, BB), blk, 0, stream>>>(X, beta, F1, NRM, UV);
    k_divfft<<<dim3(HH, BB / 2), blk, 0, stream>>>(UV, Cb, TW);
    k_colpass<<<dim3(64, 4), dim3(1024), 0, stream>>>(Cb, TW);
    k_ifinal<<<dim3(HH / FBAND, BB / 2), blk, 0, stream>>>(Cb, UV, X, out, TW);
}

// Round 8
// 202.767 us; speedup vs baseline: 1.2956x; 1.0991x over previous
//
#include <hip/hip_runtime.h>

#define BB 8
#define HH 1024
#define WW 1024
#define HW (HH*WW)
#define PI_F 3.14159265358979323846f

static __device__ __forceinline__ void gload16(const float* g, float* l)
{
    __builtin_amdgcn_global_load_lds(
        (const __attribute__((address_space(1))) void*)g,
        (__attribute__((address_space(3))) void*)l,
        16, 0, 0);
}

// bf16 pack/unpack (round-to-nearest-even)
static __device__ __forceinline__ unsigned short f2bf(float f)
{
    unsigned u = __float_as_uint(f);
    return (unsigned short)((u + 0x7fffu + ((u >> 16) & 1u)) >> 16);
}
static __device__ __forceinline__ float bf2f(unsigned short h)
{
    return __uint_as_float(((unsigned)h) << 16);
}

// ---------------------------------------------------------------------------
// Twiddle table + NRM zeroing. Per-stage concatenated: stage with half-span
// len at offset (1024-2*len), len entries exp(-i*pi*j/len)
// ---------------------------------------------------------------------------
__global__ __launch_bounds__(256) void k_twid(float2* __restrict__ tw,
                                              float* __restrict__ nrm)
{
    int tid = blockIdx.x * 256 + threadIdx.x;   // 1024 threads
    if (tid < 16) nrm[tid] = 0.0f;
    for (int len = 512; len >= 1; len >>= 1) {
        int off = 1024 - 2 * len;
        float fac = -PI_F / (float)len;
        for (int j = tid; j < len; j += 1024) {
            float sn, cs;
            sincosf(fac * (float)j, &sn, &cs);
            tw[off + j] = make_float2(cs, sn);
        }
    }
}

// ---------------------------------------------------------------------------
// Fused 3x diffusion of f_u/f_v + L2 norm — full-width band register-march.
// Output now bf16 (ushort): halves the F1 write. Norm accumulated in fp32.
// ---------------------------------------------------------------------------
#define RBAND 8
#define RAWROWS 14          // RBAND + 6

__global__ __launch_bounds__(256) void k_diff3(const float* __restrict__ su,
                                               const float* __restrict__ sv,
                                               unsigned short* __restrict__ dst,
                                               float* __restrict__ norms)
{
    __shared__ __align__(16) float A[RAWROWS * WW];   // 56 KB
    __shared__ float wsum[4];

    int bid = blockIdx.x;
    int work = (bid & 7) * 256 + (bid >> 3);
    int z = work >> 7;            // f*8+b, 0..15
    int band = work & 127;
    int f = z >> 3, b = z & 7;
    const float* s = ((f == 0) ? su : sv) + (size_t)b * HW;
    unsigned short* d = dst + (size_t)z * HW;
    int yb = band * RBAND;
    int tid = threadIdx.x;
    int w = tid >> 6, lane = tid & 63;

    for (int c = w; c < RAWROWS * 4; c += 4) {
        int row = c >> 2, seg = c & 3;
        const float* g = s + (size_t)((yb - 3 + row) & (HH - 1)) * WW
                           + (seg << 8) + (lane << 2);
        gload16(g, &A[(c << 8) + (lane << 2)]);
    }
    __syncthreads();

    const char* Ab = (const char*)A;
    int xq = tid << 4;
    int om = (xq - 16) & 4095;
    int op = (xq + 16) & 4095;

    float r[3][12];
    float i1[3][8];
    float i2[3][6];
    float sq = 0.0f;

    #pragma unroll
    for (int j = 0; j < RAWROWS; ++j) {
        {
            float4 a = *(const float4*)(Ab + j * 4096 + om);
            float4 bq = *(const float4*)(Ab + j * 4096 + xq);
            float4 cq = *(const float4*)(Ab + j * 4096 + op);
            float* rr = r[j % 3];
            rr[0] = a.x; rr[1] = a.y; rr[2] = a.z; rr[3] = a.w;
            rr[4] = bq.x; rr[5] = bq.y; rr[6] = bq.z; rr[7] = bq.w;
            rr[8] = cq.x; rr[9] = cq.y; rr[10] = cq.z; rr[11] = cq.w;
        }
        if (j >= 2) {
            const float* ru = r[(j - 2) % 3];
            const float* rc = r[(j - 1) % 3];
            const float* rd = r[j % 3];
            float* o = i1[(j - 1) % 3];
            #pragma unroll
            for (int k = 0; k < 8; ++k) {
                float c0 = rc[k + 2];
                o[k] = c0 + 0.1f * (rc[k + 1] + rc[k + 3] + ru[k + 2] + rd[k + 2] - 4.0f * c0);
            }
        }
        if (j >= 4) {
            const float* u = i1[(j - 3) % 3];
            const float* c = i1[(j - 2) % 3];
            const float* dd = i1[(j - 1) % 3];
            float* o = i2[(j - 2) % 3];
            #pragma unroll
            for (int k = 0; k < 6; ++k) {
                float c0 = c[k + 1];
                o[k] = c0 + 0.1f * (c[k] + c[k + 2] + u[k + 1] + dd[k + 1] - 4.0f * c0);
            }
        }
        if (j >= 6) {
            const float* u = i2[(j - 4) % 3];
            const float* c = i2[(j - 3) % 3];
            const float* dd = i2[(j - 2) % 3];
            float ov[4];
            #pragma unroll
            for (int k = 0; k < 4; ++k) {
                float c0 = c[k + 1];
                ov[k] = c0 + 0.1f * (c[k] + c[k + 2] + u[k + 1] + dd[k + 1] - 4.0f * c0);
            }
            ushort4 o16 = make_ushort4(f2bf(ov[0]), f2bf(ov[1]), f2bf(ov[2]), f2bf(ov[3]));
            *(ushort4*)(d + (size_t)(yb + j - 6) * WW + (tid << 2)) = o16;
            sq += ov[0] * ov[0] + ov[1] * ov[1] + ov[2] * ov[2] + ov[3] * ov[3];
        }
    }

    #pragma unroll
    for (int o = 32; o > 0; o >>= 1) sq += __shfl_down(sq, o, 64);
    if (lane == 0) wsum[w] = sq;
    __syncthreads();
    if (tid == 0)
        atomicAdd(&norms[z], wsum[0] + wsum[1] + wsum[2] + wsum[3]);
}

// ---------------------------------------------------------------------------
// Star velocities — quad-vectorized, block = one full row. F read as bf16.
// Row index XCD-swizzled: each XCD gets 128 consecutive rows per batch so
// y+-1 halo reads hit the local L2.
// ---------------------------------------------------------------------------
__global__ __launch_bounds__(256) void k_star(const float* __restrict__ X,
                                              const float* __restrict__ beta,
                                              const unsigned short* __restrict__ F,
                                              const float* __restrict__ norms,
                                              float* __restrict__ UV)
{
    int b = blockIdx.y;
    int yx = blockIdx.x;
    int y = (yx & 7) * 128 + (yx >> 3);   // bijective XCD swizzle (1024 % 8 == 0)
    int tid = threadIdx.x;
    int lane = tid & 63;
    int xq = tid << 2;
    const float* u = X + (size_t)(b * 3 + 0) * HW;
    const float* v = X + (size_t)(b * 3 + 1) * HW;
    const float* p = X + (size_t)(b * 3 + 2) * HW;
    int yr = y * WW, ym = ((y - 1) & (HH - 1)) * WW, yp = ((y + 1) & (HH - 1)) * WW;

    float4 ucq = *(const float4*)(u + yr + xq);
    float4 uuq = *(const float4*)(u + ym + xq);
    float4 udq = *(const float4*)(u + yp + xq);
    float4 vcq = *(const float4*)(v + yr + xq);
    float4 vuq = *(const float4*)(v + ym + xq);
    float4 vdq = *(const float4*)(v + yp + xq);
    float4 pcq = *(const float4*)(p + yr + xq);
    float4 puq = *(const float4*)(p + ym + xq);
    float4 pdq = *(const float4*)(p + yp + xq);
    ushort4 fuq = *(const ushort4*)(F + (size_t)(0 * BB + b) * HW + yr + xq);
    ushort4 fvq = *(const ushort4*)(F + (size_t)(1 * BB + b) * HW + yr + xq);

    float ulf = __shfl_up(ucq.w, 1, 64), urt = __shfl_down(ucq.x, 1, 64);
    float vlf = __shfl_up(vcq.w, 1, 64), vrt = __shfl_down(vcq.x, 1, 64);
    float plf = __shfl_up(pcq.w, 1, 64), prt = __shfl_down(pcq.x, 1, 64);
    if (lane == 0)  { int xm = (xq - 1) & (WW - 1); ulf = u[yr + xm]; vlf = v[yr + xm]; plf = p[yr + xm]; }
    if (lane == 63) { int xp = (xq + 4) & (WW - 1); urt = u[yr + xp]; vrt = v[yr + xp]; prt = p[yr + xp]; }

    float ue[6] = { ulf, ucq.x, ucq.y, ucq.z, ucq.w, urt };
    float ve[6] = { vlf, vcq.x, vcq.y, vcq.z, vcq.w, vrt };
    float pe[6] = { plf, pcq.x, pcq.y, pcq.z, pcq.w, prt };
    float uu_[4] = { uuq.x, uuq.y, uuq.z, uuq.w };
    float ud_[4] = { udq.x, udq.y, udq.z, udq.w };
    float vu_[4] = { vuq.x, vuq.y, vuq.z, vuq.w };
    float vd_[4] = { vdq.x, vdq.y, vdq.z, vdq.w };
    float pu_[4] = { puq.x, puq.y, puq.z, puq.w };
    float pd_[4] = { pdq.x, pdq.y, pdq.z, pdq.w };
    float fu_[4] = { bf2f(fuq.x), bf2f(fuq.y), bf2f(fuq.z), bf2f(fuq.w) };
    float fv_[4] = { bf2f(fvq.x), bf2f(fvq.y), bf2f(fvq.z), bf2f(fvq.w) };

    float sb = sqrtf(beta[b]);
    float inu = 1.0f / fmaxf(sqrtf(norms[b]), 1e-12f);
    float inv = 1.0f / fmaxf(sqrtf(norms[BB + b]), 1e-12f);

    float4 un4, vn4;
    float* unp = (float*)&un4;
    float* vnp = (float*)&vn4;
    #pragma unroll
    for (int k = 0; k < 4; ++k) {
        float ucc = ue[k + 1], vcc = ve[k + 1];
        float adv_u = ucc * (0.5f * (ue[k + 2] - ue[k])) + vcc * (0.5f * (ud_[k] - uu_[k]));
        float adv_v = ucc * (0.5f * (ve[k + 2] - ve[k])) + vcc * (0.5f * (vd_[k] - vu_[k]));
        float lap_u = ue[k] + ue[k + 2] + uu_[k] + ud_[k] - 4.0f * ucc;
        float lap_v = ve[k] + ve[k + 2] + vu_[k] + vd_[k] - 4.0f * vcc;
        float dpdx = 0.5f * (pe[k + 2] - pe[k]);
        float dpdy = 0.5f * (pd_[k] - pu_[k]);
        unp[k] = ucc + 0.01f * (-adv_u + 0.01f * lap_u - dpdx) + sb * fu_[k] * inu;
        vnp[k] = vcc + 0.01f * (-adv_v + 0.01f * lap_v - dpdy) + sb * fv_[k] * inv;
    }

    *(float4*)(UV + (size_t)(0 * BB + b) * HW + yr + xq) = un4;
    *(float4*)(UV + (size_t)(1 * BB + b) * HW + yr + xq) = vn4;
}

// ---------------------------------------------------------------------------
// float2-based FFT helpers (length 1024, LDS, 256 threads, block-wide)
// ---------------------------------------------------------------------------
static __device__ __forceinline__ void fft_dif2(float2* d, const float2* tw)
{
    int t = threadIdx.x;
    for (int s = 9; s >= 0; --s) {
        int len = 1 << s;
        int off = 1024 - 2 * len;
        __syncthreads();
        #pragma unroll
        for (int k = 0; k < 2; ++k) {
            int bt = t + (k << 8);
            int j = bt & (len - 1);
            int i = ((bt >> s) << (s + 1)) | j;
            float2 u = d[i], v = d[i + len], w = tw[off + j];
            d[i] = make_float2(u.x + v.x, u.y + v.y);
            float dr = u.x - v.x, di = u.y - v.y;
            d[i + len] = make_float2(dr * w.x - di * w.y, dr * w.y + di * w.x);
        }
    }
}

static __device__ __forceinline__ void fft_dit_inv2(float2* d, const float2* tw)
{
    int t = threadIdx.x;
    for (int s = 0; s <= 9; ++s) {
        int len = 1 << s;
        int off = 1024 - 2 * len;
        __syncthreads();
        #pragma unroll
        for (int k = 0; k < 2; ++k) {
            int bt = t + (k << 8);
            int j = bt & (len - 1);
            int i = ((bt >> s) << (s + 1)) | j;
            float2 u = d[i], v = d[i + len], w = tw[off + j];   // conj(w)
            float tr = v.x * w.x + v.y * w.y;
            float ti = v.y * w.x - v.x * w.y;
            d[i] = make_float2(u.x + tr, u.y + ti);
            d[i + len] = make_float2(u.x - tr, u.y - ti);
        }
    }
}

// ---------------------------------------------------------------------------
// Fused divergence + forward row FFT. Block = (row y, pair q). Row swizzled.
// ---------------------------------------------------------------------------
__global__ __launch_bounds__(256) void k_divfft(const float* __restrict__ UV,
                                                float2* __restrict__ dst,
                                                const float2* __restrict__ tw)
{
    __shared__ __align__(16) float2 data[1024];
    __shared__ __align__(16) float2 twl[1024];
    __shared__ __align__(16) float us0[1024], us1[1024];
    int yx = blockIdx.x, q = blockIdx.y;
    int y = (yx & 7) * 128 + (yx >> 3);   // XCD swizzle
    int b0 = 2 * q, b1 = 2 * q + 1;
    int tid = threadIdx.x, w = tid >> 6, lane = tid & 63;
    int yr = y * WW, ym = ((y - 1) & (HH - 1)) * WW, yp = ((y + 1) & (HH - 1)) * WW;
    const float* u0 = UV + (size_t)b0 * HW;
    const float* v0 = UV + (size_t)(BB + b0) * HW;
    const float* u1 = UV + (size_t)b1 * HW;
    const float* v1 = UV + (size_t)(BB + b1) * HW;

    gload16(u0 + yr + (w << 8) + (lane << 2), &us0[(w << 8) + (lane << 2)]);
    gload16(u1 + yr + (w << 8) + (lane << 2), &us1[(w << 8) + (lane << 2)]);

    for (int j = tid; j < 1024; j += 256) twl[j] = tw[j];

    int xq = tid << 2;
    float4 v0u = *(const float4*)(v0 + ym + xq);
    float4 v0d = *(const float4*)(v0 + yp + xq);
    float4 v1u = *(const float4*)(v1 + ym + xq);
    float4 v1d = *(const float4*)(v1 + yp + xq);
    __syncthreads();   // drains DMA (vmcnt) + twl

    float4 c0 = *(const float4*)&us0[xq];
    float4 c1 = *(const float4*)&us1[xq];
    float lf0 = us0[(xq - 1) & 1023], rt0 = us0[(xq + 4) & 1023];
    float lf1 = us1[(xq - 1) & 1023], rt1 = us1[(xq + 4) & 1023];
    float u0e[6] = { lf0, c0.x, c0.y, c0.z, c0.w, rt0 };
    float u1e[6] = { lf1, c1.x, c1.y, c1.z, c1.w, rt1 };
    float v0u_[4] = { v0u.x, v0u.y, v0u.z, v0u.w };
    float v0d_[4] = { v0d.x, v0d.y, v0d.z, v0d.w };
    float v1u_[4] = { v1u.x, v1u.y, v1u.z, v1u.w };
    float v1d_[4] = { v1d.x, v1d.y, v1d.z, v1d.w };
    #pragma unroll
    for (int k = 0; k < 4; ++k) {
        float d0 = 0.5f * (u0e[k + 2] - u0e[k]) + 0.5f * (v0d_[k] - v0u_[k]);
        float d1 = 0.5f * (u1e[k + 2] - u1e[k]) + 0.5f * (v1d_[k] - v1u_[k]);
        data[xq + k] = make_float2(d0, d1);
    }

    fft_dif2(data, twl);
    __syncthreads();
    size_t base = (size_t)((q << 10) + y) << 10;
    float4* dst4 = (float4*)(dst + base);
    float4* dat4 = (float4*)data;
    dst4[2 * tid] = dat4[2 * tid];
    dst4[2 * tid + 1] = dat4[2 * tid + 1];
}

// ---------------------------------------------------------------------------
// Fused column pass (unchanged from round 7): 16 cols/block, per-wave FFT.
// ---------------------------------------------------------------------------
#define CT 16
#define CSTR 1026

__global__ __launch_bounds__(1024) void k_colpass(float2* __restrict__ spec,
                                                  const float2* __restrict__ tw)
{
    __shared__ __align__(16) float2 colbuf[CT * CSTR];   // 131328 B
    __shared__ __align__(16) float2 twl[1024];           // 8192 B
    int tile = blockIdx.x, q = blockIdx.y;
    int i0 = tile * CT;
    int tid = threadIdx.x, lane = tid & 63, w = tid >> 6;
    size_t qb = (size_t)q * HW;

    twl[tid] = tw[tid];

    float2* g = spec + qb;
    #pragma unroll 4
    for (int pass = 0; pass < 16; ++pass) {
        int n = (pass << 10) + tid;
        int r = n >> 4, c = n & 15;
        colbuf[c * CSTR + r] = g[(size_t)r * 1024 + i0 + c];
    }
    __syncthreads();

    float2* d = colbuf + w * CSTR;
    int i = i0 + w;
    int kx = __brev((unsigned)i) >> 22;
    int fx = (kx < 512) ? kx : kx - 1024;
    float fx2 = (float)(fx * fx);

    for (int s = 9; s >= 0; --s) {
        int len = 1 << s, off = 1024 - 2 * len;
        asm volatile("s_waitcnt lgkmcnt(0)" ::: "memory");
        __builtin_amdgcn_sched_barrier(0);
        #pragma unroll
        for (int k = 0; k < 8; ++k) {
            int bt = lane + (k << 6);
            int j = bt & (len - 1);
            int ii = ((bt >> s) << (s + 1)) | j;
            float2 u = d[ii], v = d[ii + len], wv = twl[off + j];
            d[ii] = make_float2(u.x + v.x, u.y + v.y);
            float dr = u.x - v.x, di = u.y - v.y;
            d[ii + len] = make_float2(dr * wv.x - di * wv.y, dr * wv.y + di * wv.x);
        }
    }
    asm volatile("s_waitcnt lgkmcnt(0)" ::: "memory");
    __builtin_amdgcn_sched_barrier(0);
    const float cc = -1.0f / (4.0f * PI_F * PI_F * 1024.0f * 1024.0f); // incl. 1/(H*W)
    #pragma unroll
    for (int k = 0; k < 16; ++k) {
        int kk = lane + (k << 6);
        int ky = __brev((unsigned)kk) >> 22;
        int fy = (ky < 512) ? ky : ky - 1024;
        float k2 = fx2 + (float)(fy * fy);
        float s = (k2 > 0.0f) ? (cc / k2) : 0.0f;   // DC zeroed
        float2 v = d[kk];
        d[kk] = make_float2(v.x * s, v.y * s);
    }
    for (int s = 0; s <= 9; ++s) {
        int len = 1 << s, off = 1024 - 2 * len;
        asm volatile("s_waitcnt lgkmcnt(0)" ::: "memory");
        __builtin_amdgcn_sched_barrier(0);
        #pragma unroll
        for (int k = 0; k < 8; ++k) {
            int bt = lane + (k << 6);
            int j = bt & (len - 1);
            int ii = ((bt >> s) << (s + 1)) | j;
            float2 u = d[ii], v = d[ii + len], wv = twl[off + j];   // conj(w)
            float tr = v.x * wv.x + v.y * wv.y;
            float ti = v.y * wv.x - v.x * wv.y;
            d[ii] = make_float2(u.x + tr, u.y + ti);
            d[ii + len] = make_float2(u.x - tr, u.y - ti);
        }
    }
    asm volatile("s_waitcnt lgkmcnt(0)" ::: "memory");
    __builtin_amdgcn_sched_barrier(0);
    __syncthreads();

    #pragma unroll 4
    for (int pass = 0; pass < 16; ++pass) {
        int n = (pass << 10) + tid;
        int r = n >> 4, c = n & 15;
        g[(size_t)r * 1024 + i0 + c] = colbuf[c * CSTR + r];
    }
}

// ---------------------------------------------------------------------------
// Fused inverse row FFT + final projection. Band index XCD-swizzled.
// ---------------------------------------------------------------------------
#define FBAND 4

__global__ __launch_bounds__(256) void k_ifinal(const float2* __restrict__ spec,
                                                const float* __restrict__ UV,
                                                const float* __restrict__ X,
                                                float* __restrict__ out,
                                                const float2* __restrict__ tw)
{
    __shared__ __align__(16) float2 ring[3][1024];   // 24 KB
    __shared__ __align__(16) float2 twl[1024];       // 8 KB
    int bx = blockIdx.x, q = blockIdx.y;
    int band = (bx & 7) * 32 + (bx >> 3);   // XCD swizzle (256 % 8 == 0)
    int b0 = 2 * q, b1 = 2 * q + 1;
    int y0 = band * FBAND;
    int tid = threadIdx.x, w = tid >> 6, lane = tid & 63;

    for (int j = tid; j < 1024; j += 256) twl[j] = tw[j];

    size_t sbase = (size_t)q * HW;
    const float* u0 = UV + (size_t)(0 * BB + b0) * HW;
    const float* v0 = UV + (size_t)(BB + b0) * HW;
    const float* u1 = UV + (size_t)(0 * BB + b1) * HW;
    const float* v1 = UV + (size_t)(BB + b1) * HW;
    const float* p0 = X + (size_t)(b0 * 3 + 2) * HW;
    const float* p1 = X + (size_t)(b1 * 3 + 2) * HW;
    float* o_u0 = out + (size_t)(b0 * 3 + 0) * HW;
    float* o_v0 = out + (size_t)(b0 * 3 + 1) * HW;
    float* o_p0 = out + (size_t)(b0 * 3 + 2) * HW;
    float* o_u1 = out + (size_t)(b1 * 3 + 0) * HW;
    float* o_v1 = out + (size_t)(b1 * 3 + 1) * HW;
    float* o_p1 = out + (size_t)(b1 * 3 + 2) * HW;

    for (int rr = 0; rr < FBAND + 2; ++rr) {
        int yg = (y0 - 1 + rr) & (HH - 1);
        float2* slot = ring[rr % 3];

        __syncthreads();   // prior emit readers done before overwriting oldest slot
        const float* g = (const float*)(spec + sbase + (size_t)yg * 1024);
        for (int cch = w; cch < 8; cch += 4)
            gload16(g + (cch << 8) + (lane << 2), ((float*)slot) + (cch << 8) + (lane << 2));

        fft_dit_inv2(slot, twl);   // internal stage barriers drain DMA first
        __syncthreads();           // slot complete

        if (rr >= 2) {
            int ye = y0 + rr - 2;
            const float2* pcn = ring[(rr - 1) % 3];   // row ye
            const float2* ppm = ring[(rr - 2) % 3];   // row ye-1
            const float2* ppp = ring[rr % 3];         // row ye+1
            int xq = tid << 2;

            float4 cA = *(const float4*)&pcn[xq];
            float4 cB = *(const float4*)&pcn[xq + 2];
            float4 uA = *(const float4*)&ppm[xq];
            float4 uB = *(const float4*)&ppm[xq + 2];
            float4 dA = *(const float4*)&ppp[xq];
            float4 dB = *(const float4*)&ppp[xq + 2];
            float2 lf = pcn[(xq - 1) & 1023];
            float2 rt = pcn[(xq + 4) & 1023];

            float c0[4] = { cA.x, cA.z, cB.x, cB.z }, c1[4] = { cA.y, cA.w, cB.y, cB.w };
            float um0[4] = { uA.x, uA.z, uB.x, uB.z }, um1[4] = { uA.y, uA.w, uB.y, uB.w };
            float dp0[4] = { dA.x, dA.z, dB.x, dB.z }, dp1[4] = { dA.y, dA.w, dB.y, dB.w };
            float e0[6] = { lf.x, c0[0], c0[1], c0[2], c0[3], rt.x };
            float e1[6] = { lf.y, c1[0], c1[1], c1[2], c1[3], rt.y };

            size_t ro = (size_t)ye * WW + xq;
            float4 u0q = *(const float4*)(u0 + ro);
            float4 v0q = *(const float4*)(v0 + ro);
            float4 u1q = *(const float4*)(u1 + ro);
            float4 v1q = *(const float4*)(v1 + ro);
            float4 p0q = *(const float4*)(p0 + ro);
            float4 p1q = *(const float4*)(p1 + ro);

            float4 ou0, ov0, op0, ou1, ov1, op1;
            #pragma unroll
            for (int k = 0; k < 4; ++k) {
                ((float*)&ou0)[k] = ((float*)&u0q)[k] - 0.5f * (e0[k + 2] - e0[k]);
                ((float*)&ov0)[k] = ((float*)&v0q)[k] - 0.5f * (dp0[k] - um0[k]);
                ((float*)&op0)[k] = ((float*)&p0q)[k] + c0[k];
                ((float*)&ou1)[k] = ((float*)&u1q)[k] - 0.5f * (e1[k + 2] - e1[k]);
                ((float*)&ov1)[k] = ((float*)&v1q)[k] - 0.5f * (dp1[k] - um1[k]);
                ((float*)&op1)[k] = ((float*)&p1q)[k] + c1[k];
            }
            *(float4*)(o_u0 + ro) = ou0;
            *(float4*)(o_v0 + ro) = ov0;
            *(float4*)(o_p0 + ro) = op0;
            *(float4*)(o_u1 + ro) = ou1;
            *(float4*)(o_v1 + ro) = ov1;
            *(float4*)(o_p1 + ro) = op1;
        }
    }
}

extern "C" void kernel_launch(void* const* d_in, const int* in_sizes, int n_in,
                              void* d_out, int out_size, void* d_ws, size_t ws_size,
                              hipStream_t stream)
{
    const float* X    = (const float*)d_in[0];
    const float* beta = (const float*)d_in[1];
    const float* fu   = (const float*)d_in[2];
    const float* fv   = (const float*)d_in[3];
    float* out = (float*)d_out;
    float* ws  = (float*)d_ws;

    unsigned short* F1 = (unsigned short*)ws;     // 16M bf16 (32MB)
    float* UV  = ws + (size_t)BB * HW;            // 16M floats (64MB)
    float* Cbf = UV + (size_t)2 * BB * HW;        // 8M floats  (32MB)
    float* TWf = Cbf + (size_t)BB * HW;           // 2048 floats
    float* NRM = TWf + 2048;                      // 16 floats
    float2* Cb = (float2*)Cbf;
    float2* TW = (float2*)TWf;

    k_twid<<<4, 256, 0, stream>>>(TW, NRM);

    dim3 blk(256);

    k_diff3<<<2048, blk, 0, stream>>>(fu, fv, F1, NRM);
    k_star<<<dim3(HH, BB), blk, 0, stream>>>(X, beta, F1, NRM, UV);
    k_divfft<<<dim3(HH, BB / 2), blk, 0, stream>>>(UV, Cb, TW);
    k_colpass<<<dim3(64, 4), dim3(1024), 0, stream>>>(Cb, TW);
    k_ifinal<<<dim3(HH / FBAND, BB / 2), blk, 0, stream>>>(Cb, UV, X, out, TW);
}

// Round 9
// 201.793 us; speedup vs baseline: 1.3019x; 1.0048x over previous
//
#include <hip/hip_runtime.h>

#define BB 8
#define HH 1024
#define WW 1024
#define HW (HH*WW)
#define PI_F 3.14159265358979323846f

static __device__ __forceinline__ void gload16(const float* g, float* l)
{
    __builtin_amdgcn_global_load_lds(
        (const __attribute__((address_space(1))) void*)g,
        (__attribute__((address_space(3))) void*)l,
        16, 0, 0);
}

// bf16 pack/unpack (round-to-nearest-even)
static __device__ __forceinline__ unsigned short f2bf(float f)
{
    unsigned u = __float_as_uint(f);
    return (unsigned short)((u + 0x7fffu + ((u >> 16) & 1u)) >> 16);
}
static __device__ __forceinline__ float bf2f(unsigned short h)
{
    return __uint_as_float(((unsigned)h) << 16);
}

// ---------------------------------------------------------------------------
// Twiddle table + NRM zeroing. Per-stage concatenated: stage with half-span
// len at offset (1024-2*len), len entries exp(-i*pi*j/len)
// ---------------------------------------------------------------------------
__global__ __launch_bounds__(256) void k_twid(float2* __restrict__ tw,
                                              float* __restrict__ nrm)
{
    int tid = blockIdx.x * 256 + threadIdx.x;   // 1024 threads
    if (tid < 16) nrm[tid] = 0.0f;
    for (int len = 512; len >= 1; len >>= 1) {
        int off = 1024 - 2 * len;
        float fac = -PI_F / (float)len;
        for (int j = tid; j < len; j += 1024) {
            float sn, cs;
            sincosf(fac * (float)j, &sn, &cs);
            tw[off + j] = make_float2(cs, sn);
        }
    }
}

// ---------------------------------------------------------------------------
// Fused 3x diffusion of f_u/f_v + L2 norm — full-width band register-march.
// Output bf16 (ushort): halves the F1 write. Norm accumulated in fp32.
// ---------------------------------------------------------------------------
#define RBAND 8
#define RAWROWS 14          // RBAND + 6

__global__ __launch_bounds__(256) void k_diff3(const float* __restrict__ su,
                                               const float* __restrict__ sv,
                                               unsigned short* __restrict__ dst,
                                               float* __restrict__ norms)
{
    __shared__ __align__(16) float A[RAWROWS * WW];   // 56 KB
    __shared__ float wsum[4];

    int bid = blockIdx.x;
    int work = (bid & 7) * 256 + (bid >> 3);
    int z = work >> 7;            // f*8+b, 0..15
    int band = work & 127;
    int f = z >> 3, b = z & 7;
    const float* s = ((f == 0) ? su : sv) + (size_t)b * HW;
    unsigned short* d = dst + (size_t)z * HW;
    int yb = band * RBAND;
    int tid = threadIdx.x;
    int w = tid >> 6, lane = tid & 63;

    for (int c = w; c < RAWROWS * 4; c += 4) {
        int row = c >> 2, seg = c & 3;
        const float* g = s + (size_t)((yb - 3 + row) & (HH - 1)) * WW
                           + (seg << 8) + (lane << 2);
        gload16(g, &A[(c << 8) + (lane << 2)]);
    }
    __syncthreads();

    const char* Ab = (const char*)A;
    int xq = tid << 4;
    int om = (xq - 16) & 4095;
    int op = (xq + 16) & 4095;

    float r[3][12];
    float i1[3][8];
    float i2[3][6];
    float sq = 0.0f;

    #pragma unroll
    for (int j = 0; j < RAWROWS; ++j) {
        {
            float4 a = *(const float4*)(Ab + j * 4096 + om);
            float4 bq = *(const float4*)(Ab + j * 4096 + xq);
            float4 cq = *(const float4*)(Ab + j * 4096 + op);
            float* rr = r[j % 3];
            rr[0] = a.x; rr[1] = a.y; rr[2] = a.z; rr[3] = a.w;
            rr[4] = bq.x; rr[5] = bq.y; rr[6] = bq.z; rr[7] = bq.w;
            rr[8] = cq.x; rr[9] = cq.y; rr[10] = cq.z; rr[11] = cq.w;
        }
        if (j >= 2) {
            const float* ru = r[(j - 2) % 3];
            const float* rc = r[(j - 1) % 3];
            const float* rd = r[j % 3];
            float* o = i1[(j - 1) % 3];
            #pragma unroll
            for (int k = 0; k < 8; ++k) {
                float c0 = rc[k + 2];
                o[k] = c0 + 0.1f * (rc[k + 1] + rc[k + 3] + ru[k + 2] + rd[k + 2] - 4.0f * c0);
            }
        }
        if (j >= 4) {
            const float* u = i1[(j - 3) % 3];
            const float* c = i1[(j - 2) % 3];
            const float* dd = i1[(j - 1) % 3];
            float* o = i2[(j - 2) % 3];
            #pragma unroll
            for (int k = 0; k < 6; ++k) {
                float c0 = c[k + 1];
                o[k] = c0 + 0.1f * (c[k] + c[k + 2] + u[k + 1] + dd[k + 1] - 4.0f * c0);
            }
        }
        if (j >= 6) {
            const float* u = i2[(j - 4) % 3];
            const float* c = i2[(j - 3) % 3];
            const float* dd = i2[(j - 2) % 3];
            float ov[4];
            #pragma unroll
            for (int k = 0; k < 4; ++k) {
                float c0 = c[k + 1];
                ov[k] = c0 + 0.1f * (c[k] + c[k + 2] + u[k + 1] + dd[k + 1] - 4.0f * c0);
            }
            ushort4 o16 = make_ushort4(f2bf(ov[0]), f2bf(ov[1]), f2bf(ov[2]), f2bf(ov[3]));
            *(ushort4*)(d + (size_t)(yb + j - 6) * WW + (tid << 2)) = o16;
            sq += ov[0] * ov[0] + ov[1] * ov[1] + ov[2] * ov[2] + ov[3] * ov[3];
        }
    }

    #pragma unroll
    for (int o = 32; o > 0; o >>= 1) sq += __shfl_down(sq, o, 64);
    if (lane == 0) wsum[w] = sq;
    __syncthreads();
    if (tid == 0)
        atomicAdd(&norms[z], wsum[0] + wsum[1] + wsum[2] + wsum[3]);
}

// ---------------------------------------------------------------------------
// Star velocities — quad-vectorized, block = one full row. F read as bf16.
// Row index XCD-swizzled for L2 halo locality.
// ---------------------------------------------------------------------------
__global__ __launch_bounds__(256) void k_star(const float* __restrict__ X,
                                              const float* __restrict__ beta,
                                              const unsigned short* __restrict__ F,
                                              const float* __restrict__ norms,
                                              float* __restrict__ UV)
{
    int b = blockIdx.y;
    int yx = blockIdx.x;
    int y = (yx & 7) * 128 + (yx >> 3);   // bijective XCD swizzle (1024 % 8 == 0)
    int tid = threadIdx.x;
    int lane = tid & 63;
    int xq = tid << 2;
    const float* u = X + (size_t)(b * 3 + 0) * HW;
    const float* v = X + (size_t)(b * 3 + 1) * HW;
    const float* p = X + (size_t)(b * 3 + 2) * HW;
    int yr = y * WW, ym = ((y - 1) & (HH - 1)) * WW, yp = ((y + 1) & (HH - 1)) * WW;

    float4 ucq = *(const float4*)(u + yr + xq);
    float4 uuq = *(const float4*)(u + ym + xq);
    float4 udq = *(const float4*)(u + yp + xq);
    float4 vcq = *(const float4*)(v + yr + xq);
    float4 vuq = *(const float4*)(v + ym + xq);
    float4 vdq = *(const float4*)(v + yp + xq);
    float4 pcq = *(const float4*)(p + yr + xq);
    float4 puq = *(const float4*)(p + ym + xq);
    float4 pdq = *(const float4*)(p + yp + xq);
    ushort4 fuq = *(const ushort4*)(F + (size_t)(0 * BB + b) * HW + yr + xq);
    ushort4 fvq = *(const ushort4*)(F + (size_t)(1 * BB + b) * HW + yr + xq);

    float ulf = __shfl_up(ucq.w, 1, 64), urt = __shfl_down(ucq.x, 1, 64);
    float vlf = __shfl_up(vcq.w, 1, 64), vrt = __shfl_down(vcq.x, 1, 64);
    float plf = __shfl_up(pcq.w, 1, 64), prt = __shfl_down(pcq.x, 1, 64);
    if (lane == 0)  { int xm = (xq - 1) & (WW - 1); ulf = u[yr + xm]; vlf = v[yr + xm]; plf = p[yr + xm]; }
    if (lane == 63) { int xp = (xq + 4) & (WW - 1); urt = u[yr + xp]; vrt = v[yr + xp]; prt = p[yr + xp]; }

    float ue[6] = { ulf, ucq.x, ucq.y, ucq.z, ucq.w, urt };
    float ve[6] = { vlf, vcq.x, vcq.y, vcq.z, vcq.w, vrt };
    float pe[6] = { plf, pcq.x, pcq.y, pcq.z, pcq.w, prt };
    float uu_[4] = { uuq.x, uuq.y, uuq.z, uuq.w };
    float ud_[4] = { udq.x, udq.y, udq.z, udq.w };
    float vu_[4] = { vuq.x, vuq.y, vuq.z, vuq.w };
    float vd_[4] = { vdq.x, vdq.y, vdq.z, vdq.w };
    float pu_[4] = { puq.x, puq.y, puq.z, puq.w };
    float pd_[4] = { pdq.x, pdq.y, pdq.z, pdq.w };
    float fu_[4] = { bf2f(fuq.x), bf2f(fuq.y), bf2f(fuq.z), bf2f(fuq.w) };
    float fv_[4] = { bf2f(fvq.x), bf2f(fvq.y), bf2f(fvq.z), bf2f(fvq.w) };

    float sb = sqrtf(beta[b]);
    float inu = 1.0f / fmaxf(sqrtf(norms[b]), 1e-12f);
    float inv = 1.0f / fmaxf(sqrtf(norms[BB + b]), 1e-12f);

    float4 un4, vn4;
    float* unp = (float*)&un4;
    float* vnp = (float*)&vn4;
    #pragma unroll
    for (int k = 0; k < 4; ++k) {
        float ucc = ue[k + 1], vcc = ve[k + 1];
        float adv_u = ucc * (0.5f * (ue[k + 2] - ue[k])) + vcc * (0.5f * (ud_[k] - uu_[k]));
        float adv_v = ucc * (0.5f * (ve[k + 2] - ve[k])) + vcc * (0.5f * (vd_[k] - vu_[k]));
        float lap_u = ue[k] + ue[k + 2] + uu_[k] + ud_[k] - 4.0f * ucc;
        float lap_v = ve[k] + ve[k + 2] + vu_[k] + vd_[k] - 4.0f * vcc;
        float dpdx = 0.5f * (pe[k + 2] - pe[k]);
        float dpdy = 0.5f * (pd_[k] - pu_[k]);
        unp[k] = ucc + 0.01f * (-adv_u + 0.01f * lap_u - dpdx) + sb * fu_[k] * inu;
        vnp[k] = vcc + 0.01f * (-adv_v + 0.01f * lap_v - dpdy) + sb * fv_[k] * inv;
    }

    *(float4*)(UV + (size_t)(0 * BB + b) * HW + yr + xq) = un4;
    *(float4*)(UV + (size_t)(1 * BB + b) * HW + yr + xq) = vn4;
}

// ---------------------------------------------------------------------------
// float2-based FFT helpers (length 1024, LDS, 256 threads, block-wide)
// ---------------------------------------------------------------------------
static __device__ __forceinline__ void fft_dif2(float2* d, const float2* tw)
{
    int t = threadIdx.x;
    for (int s = 9; s >= 0; --s) {
        int len = 1 << s;
        int off = 1024 - 2 * len;
        __syncthreads();
        #pragma unroll
        for (int k = 0; k < 2; ++k) {
            int bt = t + (k << 8);
            int j = bt & (len - 1);
            int i = ((bt >> s) << (s + 1)) | j;
            float2 u = d[i], v = d[i + len], w = tw[off + j];
            d[i] = make_float2(u.x + v.x, u.y + v.y);
            float dr = u.x - v.x, di = u.y - v.y;
            d[i + len] = make_float2(dr * w.x - di * w.y, dr * w.y + di * w.x);
        }
    }
}

static __device__ __forceinline__ void fft_dit_inv2(float2* d, const float2* tw)
{
    int t = threadIdx.x;
    for (int s = 0; s <= 9; ++s) {
        int len = 1 << s;
        int off = 1024 - 2 * len;
        __syncthreads();
        #pragma unroll
        for (int k = 0; k < 2; ++k) {
            int bt = t + (k << 8);
            int j = bt & (len - 1);
            int i = ((bt >> s) << (s + 1)) | j;
            float2 u = d[i], v = d[i + len], w = tw[off + j];   // conj(w)
            float tr = v.x * w.x + v.y * w.y;
            float ti = v.y * w.x - v.x * w.y;
            d[i] = make_float2(u.x + tr, u.y + ti);
            d[i + len] = make_float2(u.x - tr, u.y - ti);
        }
    }
}

// ---------------------------------------------------------------------------
// Fused divergence + forward row FFT. Block = (row y, pair q). Row swizzled.
// ---------------------------------------------------------------------------
__global__ __launch_bounds__(256) void k_divfft(const float* __restrict__ UV,
                                                float2* __restrict__ dst,
                                                const float2* __restrict__ tw)
{
    __shared__ __align__(16) float2 data[1024];
    __shared__ __align__(16) float2 twl[1024];
    __shared__ __align__(16) float us0[1024], us1[1024];
    int yx = blockIdx.x, q = blockIdx.y;
    int y = (yx & 7) * 128 + (yx >> 3);   // XCD swizzle
    int b0 = 2 * q, b1 = 2 * q + 1;
    int tid = threadIdx.x, w = tid >> 6, lane = tid & 63;
    int yr = y * WW, ym = ((y - 1) & (HH - 1)) * WW, yp = ((y + 1) & (HH - 1)) * WW;
    const float* u0 = UV + (size_t)b0 * HW;
    const float* v0 = UV + (size_t)(BB + b0) * HW;
    const float* u1 = UV + (size_t)b1 * HW;
    const float* v1 = UV + (size_t)(BB + b1) * HW;

    gload16(u0 + yr + (w << 8) + (lane << 2), &us0[(w << 8) + (lane << 2)]);
    gload16(u1 + yr + (w << 8) + (lane << 2), &us1[(w << 8) + (lane << 2)]);

    for (int j = tid; j < 1024; j += 256) twl[j] = tw[j];

    int xq = tid << 2;
    float4 v0u = *(const float4*)(v0 + ym + xq);
    float4 v0d = *(const float4*)(v0 + yp + xq);
    float4 v1u = *(const float4*)(v1 + ym + xq);
    float4 v1d = *(const float4*)(v1 + yp + xq);
    __syncthreads();   // drains DMA (vmcnt) + twl

    float4 c0 = *(const float4*)&us0[xq];
    float4 c1 = *(const float4*)&us1[xq];
    float lf0 = us0[(xq - 1) & 1023], rt0 = us0[(xq + 4) & 1023];
    float lf1 = us1[(xq - 1) & 1023], rt1 = us1[(xq + 4) & 1023];
    float u0e[6] = { lf0, c0.x, c0.y, c0.z, c0.w, rt0 };
    float u1e[6] = { lf1, c1.x, c1.y, c1.z, c1.w, rt1 };
    float v0u_[4] = { v0u.x, v0u.y, v0u.z, v0u.w };
    float v0d_[4] = { v0d.x, v0d.y, v0d.z, v0d.w };
    float v1u_[4] = { v1u.x, v1u.y, v1u.z, v1u.w };
    float v1d_[4] = { v1d.x, v1d.y, v1d.z, v1d.w };
    #pragma unroll
    for (int k = 0; k < 4; ++k) {
        float d0 = 0.5f * (u0e[k + 2] - u0e[k]) + 0.5f * (v0d_[k] - v0u_[k]);
        float d1 = 0.5f * (u1e[k + 2] - u1e[k]) + 0.5f * (v1d_[k] - v1u_[k]);
        data[xq + k] = make_float2(d0, d1);
    }

    fft_dif2(data, twl);
    __syncthreads();
    size_t base = (size_t)((q << 10) + y) << 10;
    float4* dst4 = (float4*)(dst + base);
    float4* dat4 = (float4*)data;
    dst4[2 * tid] = dat4[2 * tid];
    dst4[2 * tid + 1] = dat4[2 * tid + 1];
}

// ---------------------------------------------------------------------------
// Fused column pass: CT=8 columns/block, 512 threads (8 waves), 2 blocks/CU
// (72 KB LDS) so one block's load/store overlaps the other's FFT chain.
// Per-wave 1024-pt FFT, wave-local (s_waitcnt lgkmcnt(0) + sched_barrier
// between stages); Poisson scale; inverse FFT; write back in place.
// ---------------------------------------------------------------------------
#define CT 8
#define CSTR 1026

__global__ __launch_bounds__(512) void k_colpass(float2* __restrict__ spec,
                                                 const float2* __restrict__ tw)
{
    __shared__ __align__(16) float2 colbuf[CT * CSTR];   // 65664 B
    __shared__ __align__(16) float2 twl[1024];           // 8192 B
    int tile = blockIdx.x, q = blockIdx.y;
    int i0 = tile * CT;
    int tid = threadIdx.x, lane = tid & 63, w = tid >> 6;
    size_t qb = (size_t)q * HW;

    twl[tid] = tw[tid];
    twl[tid + 512] = tw[tid + 512];

    float2* g = spec + qb;
    #pragma unroll 4
    for (int pass = 0; pass < 16; ++pass) {
        int n = (pass << 9) + tid;
        int r = n >> 3, c = n & 7;
        colbuf[c * CSTR + r] = g[(size_t)r * 1024 + i0 + c];
    }
    __syncthreads();

    // --- per-wave column FFT (column i0+w) ---------------------------------
    float2* d = colbuf + w * CSTR;
    int i = i0 + w;
    int kx = __brev((unsigned)i) >> 22;
    int fx = (kx < 512) ? kx : kx - 1024;
    float fx2 = (float)(fx * fx);

    for (int s = 9; s >= 0; --s) {
        int len = 1 << s, off = 1024 - 2 * len;
        asm volatile("s_waitcnt lgkmcnt(0)" ::: "memory");
        __builtin_amdgcn_sched_barrier(0);
        #pragma unroll
        for (int k = 0; k < 8; ++k) {
            int bt = lane + (k << 6);
            int j = bt & (len - 1);
            int ii = ((bt >> s) << (s + 1)) | j;
            float2 u = d[ii], v = d[ii + len], wv = twl[off + j];
            d[ii] = make_float2(u.x + v.x, u.y + v.y);
            float dr = u.x - v.x, di = u.y - v.y;
            d[ii + len] = make_float2(dr * wv.x - di * wv.y, dr * wv.y + di * wv.x);
        }
    }
    asm volatile("s_waitcnt lgkmcnt(0)" ::: "memory");
    __builtin_amdgcn_sched_barrier(0);
    const float cc = -1.0f / (4.0f * PI_F * PI_F * 1024.0f * 1024.0f); // incl. 1/(H*W)
    #pragma unroll
    for (int k = 0; k < 16; ++k) {
        int kk = lane + (k << 6);
        int ky = __brev((unsigned)kk) >> 22;
        int fy = (ky < 512) ? ky : ky - 1024;
        float k2 = fx2 + (float)(fy * fy);
        float s = (k2 > 0.0f) ? (cc / k2) : 0.0f;   // DC zeroed
        float2 v = d[kk];
        d[kk] = make_float2(v.x * s, v.y * s);
    }
    for (int s = 0; s <= 9; ++s) {
        int len = 1 << s, off = 1024 - 2 * len;
        asm volatile("s_waitcnt lgkmcnt(0)" ::: "memory");
        __builtin_amdgcn_sched_barrier(0);
        #pragma unroll
        for (int k = 0; k < 8; ++k) {
            int bt = lane + (k << 6);
            int j = bt & (len - 1);
            int ii = ((bt >> s) << (s + 1)) | j;
            float2 u = d[ii], v = d[ii + len], wv = twl[off + j];   // conj(w)
            float tr = v.x * wv.x + v.y * wv.y;
            float ti = v.y * wv.x - v.x * wv.y;
            d[ii] = make_float2(u.x + tr, u.y + ti);
            d[ii + len] = make_float2(u.x - tr, u.y - ti);
        }
    }
    asm volatile("s_waitcnt lgkmcnt(0)" ::: "memory");
    __builtin_amdgcn_sched_barrier(0);
    __syncthreads();

    #pragma unroll 4
    for (int pass = 0; pass < 16; ++pass) {
        int n = (pass << 9) + tid;
        int r = n >> 3, c = n & 7;
        g[(size_t)r * 1024 + i0 + c] = colbuf[c * CSTR + r];
    }
}

// ---------------------------------------------------------------------------
// Fused inverse row FFT + final projection. Band index XCD-swizzled.
// ---------------------------------------------------------------------------
#define FBAND 4

__global__ __launch_bounds__(256) void k_ifinal(const float2* __restrict__ spec,
                                                const float* __restrict__ UV,
                                                const float* __restrict__ X,
                                                float* __restrict__ out,
                                                const float2* __restrict__ tw)
{
    __shared__ __align__(16) float2 ring[3][1024];   // 24 KB
    __shared__ __align__(16) float2 twl[1024];       // 8 KB
    int bx = blockIdx.x, q = blockIdx.y;
    int band = (bx & 7) * 32 + (bx >> 3);   // XCD swizzle (256 % 8 == 0)
    int b0 = 2 * q, b1 = 2 * q + 1;
    int y0 = band * FBAND;
    int tid = threadIdx.x, w = tid >> 6, lane = tid & 63;

    for (int j = tid; j < 1024; j += 256) twl[j] = tw[j];

    size_t sbase = (size_t)q * HW;
    const float* u0 = UV + (size_t)(0 * BB + b0) * HW;
    const float* v0 = UV + (size_t)(BB + b0) * HW;
    const float* u1 = UV + (size_t)(0 * BB + b1) * HW;
    const float* v1 = UV + (size_t)(BB + b1) * HW;
    const float* p0 = X + (size_t)(b0 * 3 + 2) * HW;
    const float* p1 = X + (size_t)(b1 * 3 + 2) * HW;
    float* o_u0 = out + (size_t)(b0 * 3 + 0) * HW;
    float* o_v0 = out + (size_t)(b0 * 3 + 1) * HW;
    float* o_p0 = out + (size_t)(b0 * 3 + 2) * HW;
    float* o_u1 = out + (size_t)(b1 * 3 + 0) * HW;
    float* o_v1 = out + (size_t)(b1 * 3 + 1) * HW;
    float* o_p1 = out + (size_t)(b1 * 3 + 2) * HW;

    for (int rr = 0; rr < FBAND + 2; ++rr) {
        int yg = (y0 - 1 + rr) & (HH - 1);
        float2* slot = ring[rr % 3];

        __syncthreads();   // prior emit readers done before overwriting oldest slot
        const float* g = (const float*)(spec + sbase + (size_t)yg * 1024);
        for (int cch = w; cch < 8; cch += 4)
            gload16(g + (cch << 8) + (lane << 2), ((float*)slot) + (cch << 8) + (lane << 2));

        fft_dit_inv2(slot, twl);   // internal stage barriers drain DMA first
        __syncthreads();           // slot complete

        if (rr >= 2) {
            int ye = y0 + rr - 2;
            const float2* pcn = ring[(rr - 1) % 3];   // row ye
            const float2* ppm = ring[(rr - 2) % 3];   // row ye-1
            const float2* ppp = ring[rr % 3];         // row ye+1
            int xq = tid << 2;

            float4 cA = *(const float4*)&pcn[xq];
            float4 cB = *(const float4*)&pcn[xq + 2];
            float4 uA = *(const float4*)&ppm[xq];
            float4 uB = *(const float4*)&ppm[xq + 2];
            float4 dA = *(const float4*)&ppp[xq];
            float4 dB = *(const float4*)&ppp[xq + 2];
            float2 lf = pcn[(xq - 1) & 1023];
            float2 rt = pcn[(xq + 4) & 1023];

            float c0[4] = { cA.x, cA.z, cB.x, cB.z }, c1[4] = { cA.y, cA.w, cB.y, cB.w };
            float um0[4] = { uA.x, uA.z, uB.x, uB.z }, um1[4] = { uA.y, uA.w, uB.y, uB.w };
            float dp0[4] = { dA.x, dA.z, dB.x, dB.z }, dp1[4] = { dA.y, dA.w, dB.y, dB.w };
            float e0[6] = { lf.x, c0[0], c0[1], c0[2], c0[3], rt.x };
            float e1[6] = { lf.y, c1[0], c1[1], c1[2], c1[3], rt.y };

            size_t ro = (size_t)ye * WW + xq;
            float4 u0q = *(const float4*)(u0 + ro);
            float4 v0q = *(const float4*)(v0 + ro);
            float4 u1q = *(const float4*)(u1 + ro);
            float4 v1q = *(const float4*)(v1 + ro);
            float4 p0q = *(const float4*)(p0 + ro);
            float4 p1q = *(const float4*)(p1 + ro);

            float4 ou0, ov0, op0, ou1, ov1, op1;
            #pragma unroll
            for (int k = 0; k < 4; ++k) {
                ((float*)&ou0)[k] = ((float*)&u0q)[k] - 0.5f * (e0[k + 2] - e0[k]);
                ((float*)&ov0)[k] = ((float*)&v0q)[k] - 0.5f * (dp0[k] - um0[k]);
                ((float*)&op0)[k] = ((float*)&p0q)[k] + c0[k];
                ((float*)&ou1)[k] = ((float*)&u1q)[k] - 0.5f * (e1[k + 2] - e1[k]);
                ((float*)&ov1)[k] = ((float*)&v1q)[k] - 0.5f * (dp1[k] - um1[k]);
                ((float*)&op1)[k] = ((float*)&p1q)[k] + c1[k];
            }
            *(float4*)(o_u0 + ro) = ou0;
            *(float4*)(o_v0 + ro) = ov0;
            *(float4*)(o_p0 + ro) = op0;
            *(float4*)(o_u1 + ro) = ou1;
            *(float4*)(o_v1 + ro) = ov1;
            *(float4*)(o_p1 + ro) = op1;
        }
    }
}

extern "C" void kernel_launch(void* const* d_in, const int* in_sizes, int n_in,
                              void* d_out, int out_size, void* d_ws, size_t ws_size,
                              hipStream_t stream)
{
    const float* X    = (const float*)d_in[0];
    const float* beta = (const float*)d_in[1];
    const float* fu   = (const float*)d_in[2];
    const float* fv   = (const float*)d_in[3];
    float* out = (float*)d_out;
    float* ws  = (float*)d_ws;

    unsigned short* F1 = (unsigned short*)ws;     // 16M bf16 (32MB)
    float* UV  = ws + (size_t)BB * HW;            // 16M floats (64MB)
    float* Cbf = UV + (size_t)2 * BB * HW;        // 8M floats  (32MB)
    float* TWf = Cbf + (size_t)BB * HW;           // 2048 floats
    float* NRM = TWf + 2048;                      // 16 floats
    float2* Cb = (float2*)Cbf;
    float2* TW = (float2*)TWf;

    k_twid<<<4, 256, 0, stream>>>(TW, NRM);

    dim3 blk(256);

    k_diff3<<<2048, blk, 0, stream>>>(fu, fv, F1, NRM);
    k_star<<<dim3(HH, BB), blk, 0, stream>>>(X, beta, F1, NRM, UV);
    k_divfft<<<dim3(HH, BB / 2), blk, 0, stream>>>(UV, Cb, TW);
    k_colpass<<<dim3(WW / CT, 4), dim3(512), 0, stream>>>(Cb, TW);
    k_ifinal<<<dim3(HH / FBAND, BB / 2), blk, 0, stream>>>(Cb, UV, X, out, TW);
}